// Round 9
// baseline (748.730 us; speedup 1.0000x reference)
//
#include <hip/hip_runtime.h>
#include <stdint.h>

// R16: spatial x2 split of the three 512-block big-LDS MFMA kernels (base R15 = 320.6us):
//  - conv4m: 2 halves/image own 3 output rows each; LDS 21.6 -> 11.6 KB; grid 1024
//  - deconv1m: 2 halves/image own 2 of 4 parity classes; grid 1024
//  - deconv2m: 2 halves/image own 2 of 4 classes (2 waves/class, t-parity); grid 1024
// Tests mid-pipeline TLP (R3 measured 18.8% occupancy at this geometry). Traffic +37MB.

typedef unsigned short ushort_t;
typedef __bf16 bf16x8 __attribute__((ext_vector_type(8)));
typedef float f32x4 __attribute__((ext_vector_type(4)));

#define DEV static __device__ __forceinline__

DEV ushort_t f2bf(float f){
  union { float f; uint32_t u; } v; v.f = f;
  return (ushort_t)((v.u + 0x7FFFu + ((v.u >> 16) & 1u)) >> 16);
}
DEV float bf2f(ushort_t u){
  union { uint32_t u; float f; } v; v.u = ((uint32_t)u) << 16;
  return v.f;
}

// affine+relu two packed bf16 (raw) -> packed bf16
DEV uint32_t affine2(uint32_t rw, const float* ac, int ci, int nch){
  float lo = bf2f((ushort_t)(rw & 0xffffu));
  float hi = bf2f((ushort_t)(rw >> 16));
  lo = fmaxf(fmaf(ac[ci],   lo, ac[nch+ci]),   0.f);
  hi = fmaxf(fmaf(ac[ci+1], hi, ac[nch+ci+1]), 0.f);
  return (uint32_t)f2bf(lo) | ((uint32_t)f2bf(hi) << 16);
}
DEV uint4 stage_chunk(uint4 raw, const float* ac, int ci0, int nch){
  uint4 o;
  o.x = affine2(raw.x, ac, ci0+0, nch);
  o.y = affine2(raw.y, ac, ci0+2, nch);
  o.z = affine2(raw.z, ac, ci0+4, nch);
  o.w = affine2(raw.w, ac, ci0+6, nch);
  return o;
}

// ---------------- header (stats/coeff) offsets in floats ----------------
#define H_XS   0
#define H_S2   64
#define H_Q2   96
#define H_S3   192
#define H_Q3   256
#define H_S4   448
#define H_Q4   512
#define H_DS0  704
#define H_DQ0  768
#define H_DS1  960
#define H_DQ1  992
#define H_DS2  1088
#define H_DQ2  1104
#define H_ZN   1152   // [512]  sum of z^2 per row (softmax takes sqrtf)
#define H_MN   1664   // [2000] sum of mem^2 per row (softmax takes sqrtf)
#define H_BUK  4096   // 16 bucket banks of 1280 floats each
#define NBUK   16
#define BSTRIDE 1280
#define HDR_FLOATS (H_BUK + NBUK*BSTRIDE)

// packed-weight (bf16) offsets in WPK
#define OW2 0        // [32][160]  k=tap*16+ci, taps 0..9 (tap9 = zero pad)
#define OW3 5120     // [64][288]  k=tap*32+ci
#define OW4 23552    // [64][576]  k=tap*64+ci
#define OD0 60416    // 4 classes [64][K], K={256,128,128,64}
#define OD1 97280    // 4 classes [32][K], K={64,128,128,256}
#define OD2 115712   // 4 classes [16][32]
#define NWPK 117760

#define SIMSTRIDE 1024000   // 512*2000
#define ZHSTRIDE  1179648   // 512*2304
#define NSPLA 8             // split-K partials for GEMM1 (512 blocks)
#define NSPLB 7             // split-K partials for GEMM2 (504 blocks)

// k_prep block ranges: xstats, wprep, mem tiles (32m x 128f)
#define PREP_XS 256
#define PREP_W2 (PREP_XS + 460)      // 460*256 >= NWPK
#define PREP_TOT (PREP_W2 + 63*18)   // 63 mtiles * 18 ftiles = 1134

DEV float* bkt(float* hdr, int blk){ return hdr + H_BUK + (size_t)(blk & (NBUK-1))*BSTRIDE; }

DEV void coef_lds(const float* __restrict__ hdr, int offS, int offQ,
                  const float* __restrict__ g, const float* __restrict__ be,
                  float* ac, int nch, float invN, int tid){
  if (tid < nch){
    float s = 0.f, q = 0.f;
    #pragma unroll
    for (int k=0;k<NBUK;k++){
      s += hdr[H_BUK + k*BSTRIDE + offS + tid];
      q += hdr[H_BUK + k*BSTRIDE + offQ + tid];
    }
    float m = s*invN;
    float v = q*invN - m*m;
    float a = g[tid]*rsqrtf(v + 1e-5f);
    ac[tid] = a;
    ac[nch+tid] = be[tid] - m*a;
  }
}

// ---------------- fused prep: xstats, wprep, mem tiles (bf16 + transpose + norms) ----------------
__global__ __launch_bounds__(256) void k_prep(
    const float* __restrict__ mem, ushort_t* __restrict__ mbf, ushort_t* __restrict__ mt,
    float* __restrict__ hdr,
    const float* __restrict__ c2w, const float* __restrict__ c3w, const float* __restrict__ c4w,
    const float* __restrict__ d0w, const float* __restrict__ d1w, const float* __restrict__ d2w,
    ushort_t* __restrict__ WPK, const float* __restrict__ x){
  __shared__ ushort_t smu[32*132];    // mem branch: bf16 tile [32m][128f +4 pad]; xstats: 8 floats
  const int blk = blockIdx.x, tid = threadIdx.x;
  if (blk < PREP_XS){
    // xstats: strided-sampled input stats for bn1 fold (256 blocks, grid-stride)
    float* sm = (float*)smu;
    float s = 0.f, q = 0.f;
    const int total = 512*49*49;
    for (int idx = blk*256 + tid; idx < total; idx += 256*256){
      int b = idx / 2401;
      int r = idx - b*2401;
      int i = r / 49, j = r - i*49;
      float v = 0.f;
      if (i > 0 && j > 0) v = x[(size_t)b*9216 + (2*i-1)*96 + (2*j-1)];
      s += v; q += v*v;
    }
    for (int o=32;o;o>>=1){ s += __shfl_down(s,o,64); q += __shfl_down(q,o,64); }
    int w = tid>>6;
    if ((tid&63)==0){ sm[w*2]=s; sm[w*2+1]=q; }
    __syncthreads();
    if (tid==0){
      float* bk = bkt(hdr, blk);
      atomicAdd(&bk[H_XS+0], sm[0]+sm[2]+sm[4]+sm[6]);
      atomicAdd(&bk[H_XS+1], sm[1]+sm[3]+sm[5]+sm[7]);
    }
  } else if (blk < PREP_W2){
    // weight pack
    int i = (blk - PREP_XS)*256 + tid;
    if (i >= NWPK) return;
    float val = 0.f;
    if (i < OW3){                       // conv2 [32][160]
      int co = i/160, k = i - co*160, tap = k>>4, ci = k&15;
      if (tap < 9) val = c2w[(co*16+ci)*9+tap];
    } else if (i < OW4){                // conv3 [64][288]
      int r = i - OW3; int co = r/288, k = r - co*288, tap = k>>5, ci = k&31;
      val = c3w[(co*32+ci)*9+tap];
    } else if (i < OD0){                // conv4 [64][576]
      int r = i - OW4; int co = r/576, k = r - co*576, tap = k>>6, ci = k&63;
      val = c4w[(co*64+ci)*9+tap];
    } else if (i < OD1){                // deconv0 classes
      int r = i - OD0;
      const int base[4]={0,16384,24576,32768}, K[4]={256,128,128,64};
      const int T0[4][4] = {{0,2,6,8},{1,7,0,0},{3,5,0,0},{4,0,0,0}};
      int cl = (r<16384)?0:(r<24576)?1:(r<32768)?2:3;
      int rr = r - base[cl]; int co = rr/K[cl], k = rr - co*K[cl], t = k>>6, ci = k&63;
      val = d0w[(ci*64+co)*9 + T0[cl][t]];
    } else if (i < OD2){                // deconv1 classes
      int r = i - OD1;
      const int base[4]={0,2048,6144,10240}, K[4]={64,128,128,256};
      const int T1[4][4] = {{4,0,0,0},{3,5,0,0},{1,7,0,0},{0,2,6,8}};
      int cl = (r<2048)?0:(r<6144)?1:(r<10240)?2:3;
      int rr = r - base[cl]; int co = rr/K[cl], k = rr - co*K[cl], t = k>>6, ci = k&63;
      val = d1w[(ci*32+co)*9 + T1[cl][t]];
    } else {                            // deconv2 classes [4][16][32]
      int r = i - OD2;
      int cl = r>>9, s = r&511, co = s>>5, ci = s&31;
      const int pis[4]={0,0,1,1}, pjs[4]={0,1,0,1};
      val = d2w[((ci*16+co)*2 + (1-pis[cl]))*2 + (1-pjs[cl])];
    }
    WPK[i] = f2bf(val);
  } else {
    // 32m x 128f tile of memory: f32x4 read once, write MEMBF (uint2) + MEMT + norm^2 partials
    const int mb = blk - PREP_W2;
    const int ft = mb % 18, mtile = mb / 18;
    const int tx = tid & 31, ty = tid >> 5;
    #pragma unroll
    for (int r0=0;r0<4;r0++){
      int m = mtile*32 + r0*8 + ty;
      int f = ft*128 + tx*4;
      f32x4 v = {0.f,0.f,0.f,0.f};
      if (m < 2000) v = *(const f32x4*)&mem[(size_t)m*2304 + f];
      ushort_t h0=f2bf(v[0]), h1=f2bf(v[1]), h2=f2bf(v[2]), h3=f2bf(v[3]);
      uint2 pk = make_uint2((uint32_t)h0 | ((uint32_t)h1<<16), (uint32_t)h2 | ((uint32_t)h3<<16));
      *(uint2*)&smu[(r0*8+ty)*132 + tx*4] = pk;
      if (m < 2000) *(uint2*)&mbf[(size_t)m*2304 + f] = pk;
      float p = v[0]*v[0] + v[1]*v[1] + v[2]*v[2] + v[3]*v[3];
      for (int o=16;o;o>>=1) p += __shfl_down(p, o, 32);
      if (tx==0 && m<2000) atomicAdd(&hdr[H_MN+m], p);
    }
    __syncthreads();
    #pragma unroll
    for (int ff=0; ff<16; ff++){
      int fl = ff*8 + ty;
      mt[(size_t)(ft*128 + fl)*2016 + mtile*32 + tx] = smu[tx*132 + fl];
    }
  }
}

// ---------------- conv2 (MFMA): 16->32, 3x3 s2 p1; writes H2CL [b][625][32] raw bf16 ----------------
__global__ __launch_bounds__(256) void k_conv2m(
    const float* __restrict__ x, const ushort_t* __restrict__ WPK, const float* __restrict__ b2g,
    const float* __restrict__ c1w, const float* __restrict__ c1b,
    const float* __restrict__ bn1g, const float* __restrict__ bn1b,
    float* __restrict__ hdr, ushort_t* __restrict__ out){
  __shared__ ushort_t inp[27*51*16];    // [row][col][ci16], halo'd 51-grid rows [2*ro..2*ro+26]
  __shared__ float ac[32];
  const int blk = blockIdx.x, b = blk>>1, h = blk&1, tid = threadIdx.x;
  const int ro = h*13, nr = h?12:13, npos = nr*25, ntiles = (npos+15)>>4;
  if (tid < 16){
    float sx=0.f, qx=0.f;
    #pragma unroll
    for (int k=0;k<NBUK;k++){ sx += hdr[H_BUK+k*BSTRIDE+H_XS]; qx += hdr[H_BUK+k*BSTRIDE+H_XS+1]; }
    const float N = 512.f*49.f*49.f;
    float mx = sx/N, vx = qx/N - mx*mx;
    float mean = c1w[tid]*mx + c1b[tid];
    float a = bn1g[tid]*rsqrtf(c1w[tid]*c1w[tid]*vx + 1e-5f);
    ac[tid] = a*c1w[tid];
    ac[16+tid] = a*(c1b[tid]-mean) + bn1b[tid];
  }
  __syncthreads();
  for (int e = tid; e < 27*51; e += 256){
    int lr = e/51, gc = e - lr*51;
    int grg = 2*ro + lr;
    bool inside = (grg>=1 && grg<=49 && gc>=1 && gc<=49);
    float v = 0.f;
    if (grg>=2 && grg<=49 && gc>=2 && gc<=49) v = x[(size_t)b*9216 + (2*grg-3)*96 + (2*gc-3)];
    ushort_t hv[16];
    if (inside){
      #pragma unroll
      for (int c=0;c<16;c++) hv[c] = f2bf(fmaxf(fmaf(ac[c], v, ac[16+c]), 0.f));
    } else {
      #pragma unroll
      for (int c=0;c<16;c++) hv[c] = 0;
    }
    uint32_t w0[8];
    #pragma unroll
    for (int c=0;c<8;c++) w0[c] = (uint32_t)hv[2*c] | ((uint32_t)hv[2*c+1]<<16);
    uint4* dst = (uint4*)&inp[e*16];
    dst[0] = make_uint4(w0[0],w0[1],w0[2],w0[3]);
    dst[1] = make_uint4(w0[4],w0[5],w0[6],w0[7]);
  }
  __syncthreads();
  const int wv = tid>>6, lane = tid&63, r = lane&15, q = lane>>4;
  const int cotile = wv&1;
  bf16x8 af[5];
  #pragma unroll
  for (int c=0;c<5;c++) af[c] = *(const bf16x8*)(WPK + OW2 + (cotile*16+r)*160 + c*32 + q*8);
  float biasr[4];
  #pragma unroll
  for (int v=0;v<4;v++) biasr[v] = b2g[cotile*16 + q*4 + v];
  const int TOFF[10] = {0,1,2,51,52,53,102,103,104,0};
  const int qhi = q>>1, ci0 = (q&1)*8;
  float sacc[4]={0,0,0,0}, qacc[4]={0,0,0,0};
  for (int t = wv>>1; t < ntiles; t += 2){
    int p = t*16 + r;
    bool ok = p < npos;
    int pc = ok ? p : 0;
    int a_ = pc/25, c_ = pc - a_*25;
    int pb = (2*a_)*51 + 2*c_;
    f32x4 acc = {0.f,0.f,0.f,0.f};
    #pragma unroll
    for (int c=0;c<5;c++){
      int toff = qhi ? TOFF[2*c+1] : TOFF[2*c];
      bf16x8 bv = *(const bf16x8*)&inp[(pb + toff)*16 + ci0];
      acc = __builtin_amdgcn_mfma_f32_16x16x32_bf16(af[c], bv, acc, 0, 0, 0);
    }
    if (ok){
      int pg = (ro + a_)*25 + c_;
      ushort_t pk[4];
      #pragma unroll
      for (int reg=0;reg<4;reg++){
        float y = acc[reg] + biasr[reg];
        pk[reg] = f2bf(y);
        sacc[reg] += y; qacc[reg] += y*y;
      }
      *(uint2*)&out[((size_t)b*625 + pg)*32 + cotile*16 + q*4] =
        make_uint2((uint32_t)pk[0] | ((uint32_t)pk[1]<<16), (uint32_t)pk[2] | ((uint32_t)pk[3]<<16));
    }
  }
  float* bk = bkt(hdr, blk);
  #pragma unroll
  for (int reg=0;reg<4;reg++){
    float s = sacc[reg], qq = qacc[reg];
    for (int o=8;o;o>>=1){ s += __shfl_down(s,o,16); qq += __shfl_down(qq,o,16); }
    if (r==0){ atomicAdd(&bk[H_S2+cotile*16+q*4+reg], s); atomicAdd(&bk[H_Q2+cotile*16+q*4+reg], qq); }
  }
}

// ---------------- conv3 (MFMA): 32->64, 3x3 s2 p1, 25->13; 2 spatial halves per image ----------------
__global__ __launch_bounds__(256) void k_conv3m(
    const ushort_t* __restrict__ h2, const ushort_t* __restrict__ WPK, const float* __restrict__ b3g,
    const float* __restrict__ g, const float* __restrict__ be,
    float* __restrict__ hdr, ushort_t* __restrict__ out){
  __shared__ ushort_t inp[15*27*32];   // [lr][lc][ci32], chunk-swizzled
  __shared__ float ac[64];
  const int blk = blockIdx.x, b = blk>>1, h = blk&1, tid = threadIdx.x;
  const int a0 = h*7, na = h?6:7, npos = na*13, ntiles = (npos+15)>>4, nrows = 2*na+1;
  coef_lds(hdr, H_S2, H_Q2, g, be, ac, 32, 1.f/(512.f*625.f), tid);
  __syncthreads();
  for (int e = tid; e < nrows*27*4; e += 256){
    int cell = e>>2, ch = e&3;
    int lr = cell/27, lc = cell - lr*27;
    int ii = 2*a0 - 1 + lr, j = lc - 1;
    uint4 val = make_uint4(0,0,0,0);
    if ((unsigned)ii < 25u && (unsigned)j < 25u){
      uint4 raw = *(const uint4*)&h2[((size_t)b*625 + ii*25 + j)*32 + ch*8];
      val = stage_chunk(raw, ac, ch*8, 32);
    }
    int slot = ch ^ ((cell>>1)&3);
    *(uint4*)&inp[cell*32 + slot*8] = val;
  }
  __syncthreads();
  const int wv = tid>>6, lane = tid&63, r = lane&15, q = lane>>4;
  bf16x8 af[9];
  #pragma unroll
  for (int c=0;c<9;c++) af[c] = *(const bf16x8*)(WPK + OW3 + (wv*16+r)*288 + c*32 + q*8);
  float biasr[4];
  #pragma unroll
  for (int v=0;v<4;v++) biasr[v] = b3g[wv*16 + q*4 + v];
  const int TOFF[9] = {0,1,2,27,28,29,54,55,56};
  float sacc[4]={0,0,0,0}, qacc[4]={0,0,0,0};
  for (int t = 0; t < ntiles; t++){
    int p = t*16 + r;
    bool ok = p < npos;
    int pc = ok ? p : 0;
    int a_ = pc/13, c_ = pc - a_*13;
    int pb = (2*a_)*27 + 2*c_;
    f32x4 acc = {0.f,0.f,0.f,0.f};
    #pragma unroll
    for (int c=0;c<9;c++){
      int cell = pb + TOFF[c];
      int slot = q ^ ((cell>>1)&3);
      bf16x8 bv = *(const bf16x8*)&inp[cell*32 + slot*8];
      acc = __builtin_amdgcn_mfma_f32_16x16x32_bf16(af[c], bv, acc, 0, 0, 0);
    }
    if (ok){
      int pos = (a0 + a_)*13 + c_;
      ushort_t pk[4];
      #pragma unroll
      for (int reg=0;reg<4;reg++){
        float y = acc[reg] + biasr[reg];
        pk[reg] = f2bf(y);
        sacc[reg] += y; qacc[reg] += y*y;
      }
      *(uint2*)&out[((size_t)b*169 + pos)*64 + wv*16 + q*4] =
        make_uint2((uint32_t)pk[0] | ((uint32_t)pk[1]<<16), (uint32_t)pk[2] | ((uint32_t)pk[3]<<16));
    }
  }
  float* bk = bkt(hdr, blk);
  #pragma unroll
  for (int reg=0;reg<4;reg++){
    float s = sacc[reg], qq = qacc[reg];
    for (int o=8;o;o>>=1){ s += __shfl_down(s,o,16); qq += __shfl_down(qq,o,16); }
    if (r==0){ atomicAdd(&bk[H_S3+wv*16+q*4+reg], s); atomicAdd(&bk[H_Q3+wv*16+q*4+reg], qq); }
  }
}

// ---------------- conv4 (MFMA): 64->64, 3x3 s2 p0, 13->6; 2 row-halves per image, grid 1024 ----------------
__global__ __launch_bounds__(256) void k_conv4m(
    const ushort_t* __restrict__ h3, const ushort_t* __restrict__ WPK, const float* __restrict__ b4g,
    const float* __restrict__ g, const float* __restrict__ be,
    float* __restrict__ hdr, float* __restrict__ out){
  __shared__ ushort_t inp[91*64];      // [7 rows x 13 cols][ci64], chunk-swizzled (local rows 6h..6h+6)
  __shared__ float ac[128];
  const int blk = blockIdx.x, b = blk>>1, h = blk&1, tid = threadIdx.x;
  coef_lds(hdr, H_S3, H_Q3, g, be, ac, 64, 1.f/(512.f*169.f), tid);
  __syncthreads();
  for (int e = tid; e < 91*8; e += 256){
    int cell = e>>3, ch = e&7;
    int lr = cell/13, lc = cell - lr*13;
    int gr = 6*h + lr;                  // global row 0..12
    uint4 raw = *(const uint4*)&h3[((size_t)b*169 + gr*13 + lc)*64 + ch*8];
    uint4 val = stage_chunk(raw, ac, ch*8, 64);
    int slot = ch ^ ((cell>>1)&7);
    *(uint4*)&inp[cell*64 + slot*8] = val;
  }
  __syncthreads();
  const int wv = tid>>6, lane = tid&63, r = lane&15, q = lane>>4;
  bf16x8 af[18];
  #pragma unroll
  for (int c=0;c<18;c++) af[c] = *(const bf16x8*)(WPK + OW4 + (wv*16+r)*576 + c*32 + q*8);
  float biasr[4];
  #pragma unroll
  for (int v=0;v<4;v++) biasr[v] = b4g[wv*16 + q*4 + v];
  const int TOFF[9] = {0,1,2,13,14,15,26,27,28};
  float sacc[4]={0,0,0,0}, qacc[4]={0,0,0,0};
  for (int t = 0; t < 2; t++){
    int p = t*16 + r;                   // local position in 18 (3 rows x 6 cols)
    bool ok = p < 18;
    int pc = ok ? p : 0;
    int la = pc/6, c_ = pc - la*6;      // la in [0,3)
    int a_ = 3*h + la;                  // global output row
    int pb = (2*la)*13 + 2*c_;          // local cell base (local row = 2a_-6h = 2la)
    f32x4 acc = {0.f,0.f,0.f,0.f};
    #pragma unroll
    for (int c=0;c<18;c++){
      int cell = pb + TOFF[c>>1];
      int chunk = (c&1)*4 + q;
      int slot = chunk ^ ((cell>>1)&7);
      bf16x8 bv = *(const bf16x8*)&inp[cell*64 + slot*8];
      acc = __builtin_amdgcn_mfma_f32_16x16x32_bf16(af[c], bv, acc, 0, 0, 0);
    }
    if (ok){
      int pg = a_*6 + c_;               // global position
      #pragma unroll
      for (int reg=0;reg<4;reg++){
        float y = acc[reg] + biasr[reg];
        out[((size_t)b*64 + wv*16 + q*4 + reg)*36 + pg] = y;
        sacc[reg] += y; qacc[reg] += y*y;
      }
    }
  }
  float* bk = bkt(hdr, blk);
  #pragma unroll
  for (int reg=0;reg<4;reg++){
    float s = sacc[reg], qq = qacc[reg];
    for (int o=8;o;o>>=1){ s += __shfl_down(s,o,16); qq += __shfl_down(qq,o,16); }
    if (r==0){ atomicAdd(&bk[H_S4+wv*16+q*4+reg], s); atomicAdd(&bk[H_Q4+wv*16+q*4+reg], qq); }
  }
}

// ---------------- GEMM1 with fused z = relu(bn4(ZRAW)) on A-stage + z-norm^2 atomics ----------------
// A: ZRAW fp32 [512][2304] (k = c*36+p), B: MEMBF bf16 [2000][2304], D: SIMP NSPLA partials
__global__ __launch_bounds__(256) void k_gemmA(
    const float* __restrict__ ZR, const ushort_t* __restrict__ Bm, float* __restrict__ D,
    const float* __restrict__ g, const float* __restrict__ be, float* __restrict__ hdr){
  __shared__ __align__(16) ushort_t lB[128*40];
  __shared__ __align__(16) ushort_t lA[128*40];
  __shared__ float ac[128];
  const int blk = blockIdx.x;
  const int s = blk >> 6, t = blk & 63;          // 8 splits x 64 tiles = 512 blocks
  const int bi = t >> 4, bj = t & 15;
  const int m0 = bi*128, n0 = bj*128;
  const int k0 = s*9, k1 = k0 + 9;               // 72 k-steps / 8
  const int tid = threadIdx.x;
  coef_lds(hdr, H_S4, H_Q4, g, be, ac, 64, 1.f/(512.f*36.f), tid);
  const int lane = tid & 63, wv = tid >> 6;
  const int r = lane & 15, q = lane >> 4;
  const int wr = wv >> 1, wc = wv & 1;
  const bool bj0 = (bj == 0);
  float* Ds = D + (size_t)s*SIMSTRIDE;
  const int srow = tid >> 1, skq = (tid & 1) * 16;
  const bool bok = (n0 + srow) < 2000;
  const ushort_t* pb = Bm + (size_t)(n0 + srow)*2304 + skq;
  const float*    pa = ZR + (size_t)(m0 + srow)*2304 + skq;
  uint4* wB = (uint4*)&lB[srow*40 + skq];
  uint4* wA = (uint4*)&lA[srow*40 + skq];
  const uint4 zz = make_uint4(0,0,0,0);
  uint4 rb0 = bok ? *(const uint4*)(pb + (size_t)k0*32)     : zz;
  uint4 rb1 = bok ? *(const uint4*)(pb + (size_t)k0*32 + 8) : zz;
  f32x4 raA[4];
  #pragma unroll
  for (int i=0;i<4;i++) raA[i] = *(const f32x4*)(pa + (size_t)k0*32 + i*4);
  f32x4 acc[4][4];
  #pragma unroll
  for (int i=0;i<4;i++)
    #pragma unroll
    for (int j=0;j<4;j++) acc[i][j] = (f32x4){0.f,0.f,0.f,0.f};
  float zsq = 0.f;
  __syncthreads();   // ac ready
  for (int k=k0; k<k1; k++){
    if (k > k0) __syncthreads();
    wB[0] = rb0; wB[1] = rb1;
    {
      const int kb = k*32 + skq;
      uint32_t pw[8];
      #pragma unroll
      for (int jj=0;jj<8;jj++){
        float v0 = raA[jj>>1][(jj&1)*2+0];
        float v1 = raA[jj>>1][(jj&1)*2+1];
        int c0 = (kb + 2*jj) / 36;
        int c1 = (kb + 2*jj + 1) / 36;
        float h0 = fmaxf(fmaf(ac[c0], v0, ac[64+c0]), 0.f);
        float h1 = fmaxf(fmaf(ac[c1], v1, ac[64+c1]), 0.f);
        if (bj0) zsq += h0*h0 + h1*h1;
        pw[jj] = (uint32_t)f2bf(h0) | ((uint32_t)f2bf(h1) << 16);
      }
      wA[0] = make_uint4(pw[0],pw[1],pw[2],pw[3]);
      wA[1] = make_uint4(pw[4],pw[5],pw[6],pw[7]);
    }
    if (k+1 < k1){
      const ushort_t* nb = pb + (size_t)(k+1)*32;
      rb0 = bok ? *(const uint4*)(nb)     : zz;
      rb1 = bok ? *(const uint4*)(nb + 8) : zz;
      const float* na = pa + (size_t)(k+1)*32;
      #pragma unroll
      for (int i=0;i<4;i++) raA[i] = *(const f32x4*)(na + i*4);
    }
    __syncthreads();
    bf16x8 aF[4], bF[4];
    #pragma unroll
    for (int mt=0;mt<4;mt++) aF[mt] = *(const bf16x8*)&lA[(wr*64+mt*16+r)*40 + q*8];
    #pragma unroll
    for (int nt=0;nt<4;nt++) bF[nt] = *(const bf16x8*)&lB[(wc*64+nt*16+r)*40 + q*8];
    #pragma unroll
    for (int mt=0;mt<4;mt++)
      #pragma unroll
      for (int nt=0;nt<4;nt++)
        acc[mt][nt] = __builtin_amdgcn_mfma_f32_16x16x32_bf16(aF[mt], bF[nt], acc[mt][nt], 0, 0, 0);
  }
  if (bj0){
    zsq += __shfl_down(zsq, 1, 64);
    if ((tid & 1) == 0) atomicAdd(&hdr[H_ZN + m0 + srow], zsq);
  }
  #pragma unroll
  for (int mt=0;mt<4;mt++){
    int row = m0 + wr*64 + mt*16 + q*4;
    #pragma unroll
    for (int nt=0;nt<4;nt++){
      int col = n0 + wc*64 + nt*16 + r;
      if (col < 2000){
        #pragma unroll
        for (int reg=0;reg<4;reg++)
          Ds[(size_t)(row+reg)*2000 + col] = acc[mt][nt][reg];
      }
    }
  }
}

// ---------------- blocked GEMM, split-K (GEMM2) ----------------
__global__ __launch_bounds__(256) void k_gemmB(const ushort_t* __restrict__ A, const ushort_t* __restrict__ Bm,
                                               float* __restrict__ D, int Nb, int N, int Kp, int kch,
                                               int tiles, int ksp, size_t dstride){
  __shared__ __align__(16) ushort_t lB[128*40];
  const int blk = blockIdx.x;
  const int s = blk / tiles, t = blk - s*tiles;
  const int bi = t / Nb, bj = t - bi*Nb;
  const int m0 = bi*128, n0 = bj*128;
  const int k0 = s*ksp, k1 = min(kch, k0 + ksp);
  const int tid = threadIdx.x;
  const int lane = tid & 63, wv = tid >> 6;
  const int r = lane & 15, q = lane >> 4;
  const int wr = wv >> 1, wc = wv & 1;
  float* Ds = D + (size_t)s*dstride;
  const int srow = tid >> 1, skq = (tid & 1) * 16;
  const bool bok = (n0 + srow) < N;
  const ushort_t* pb = Bm + (size_t)(n0 + srow)*Kp + skq;
  uint4* wB = (uint4*)&lB[srow*40 + skq];
  const uint4 zz = make_uint4(0,0,0,0);
  uint4 rb0 = bok ? *(const uint4*)(pb + k0*32)     : zz;
  uint4 rb1 = bok ? *(const uint4*)(pb + k0*32 + 8) : zz;
  const ushort_t* pa = A + (size_t)(m0 + wr*64 + r)*Kp + q*8;
  bf16x8 aN[4];
  #pragma unroll
  for (int mt=0;mt<4;mt++) aN[mt] = *(const bf16x8*)(pa + k0*32 + (size_t)(mt*16)*Kp);
  f32x4 acc[4][4];
  #pragma unroll
  for (int i=0;i<4;i++)
    #pragma unroll
    for (int j=0;j<4;j++) acc[i][j] = (f32x4){0.f,0.f,0.f,0.f};
  for (int k=k0; k<k1; k++){
    if (k > k0) __syncthreads();
    wB[0] = rb0; wB[1] = rb1;
    bf16x8 aF[4];
    #pragma unroll
    for (int mt=0;mt<4;mt++) aF[mt] = aN[mt];
    if (k+1 < k1){
      const ushort_t* nb = pb + (k+1)*32;
      rb0 = bok ? *(const uint4*)(nb)     : zz;
      rb1 = bok ? *(const uint4*)(nb + 8) : zz;
      const ushort_t* na = pa + (k+1)*32;
      #pragma unroll
      for (int mt=0;mt<4;mt++) aN[mt] = *(const bf16x8*)(na + (size_t)(mt*16)*Kp);
    }
    __syncthreads();
    bf16x8 bF[4];
    #pragma unroll
    for (int nt=0;nt<4;nt++) bF[nt] = *(const bf16x8*)&lB[(wc*64+nt*16+r)*40 + q*8];
    #pragma unroll
    for (int mt=0;mt<4;mt++)
      #pragma unroll
      for (int nt=0;nt<4;nt++)
        acc[mt][nt] = __builtin_amdgcn_mfma_f32_16x16x32_bf16(aF[mt], bF[nt], acc[mt][nt], 0, 0, 0);
  }
  #pragma unroll
  for (int mt=0;mt<4;mt++){
    int row = m0 + wr*64 + mt*16 + q*4;
    #pragma unroll
    for (int nt=0;nt<4;nt++){
      int col = n0 + wc*64 + nt*16 + r;
      if (col < N){
        #pragma unroll
        for (int reg=0;reg<4;reg++)
          Ds[(size_t)(row+reg)*N + col] = acc[mt][nt][reg];
      }
    }
  }
}

// softmax over M=2000 (sums NSPLA split-K partials) + hard-shrink + L1 renorm -> bf16
__global__ __launch_bounds__(256) void k_softmax(const float* __restrict__ sim, float* __restrict__ hdr,
                                                 ushort_t* __restrict__ wbf){
  __shared__ float e[2000];
  __shared__ float red[8];
  const int b = blockIdx.x, tid = threadIdx.x;
  const float znb = sqrtf(hdr[H_ZN+b]);
  float part = 0.f;
  for (int m=tid;m<2000;m+=256){
    size_t ix = (size_t)b*2000+m;
    float sv = 0.f;
    #pragma unroll
    for (int j=0;j<NSPLA;j++) sv += sim[ix + (size_t)j*SIMSTRIDE];
    float mnb = sqrtf(hdr[H_MN+m]);
    float s = sv / fmaxf(znb * mnb, 1e-8f);
    float ev = __expf(s);
    e[m] = ev; part += ev;
  }
  for (int o=32;o;o>>=1) part += __shfl_down(part,o,64);
  if ((tid&63)==0) red[tid>>6] = part;
  __syncthreads();
  const float denom = red[0]+red[1]+red[2]+red[3];
  const float t = 1.0f/2000.0f;
  float part2 = 0.f;
  for (int m=tid;m<2000;m+=256){
    float w = e[m]/denom;
    float d = w - t;
    float sh = fmaxf(d,0.f)*w/(fabsf(d)+0.01f);
    e[m] = sh; part2 += sh;
  }
  for (int o=32;o;o>>=1) part2 += __shfl_down(part2,o,64);
  if ((tid&63)==0) red[4+(tid>>6)] = part2;
  __syncthreads();
  const float inv = 1.0f/(red[4]+red[5]+red[6]+red[7]);
  for (int m=tid;m<2016;m+=256){
    ushort_t o = 0;
    if (m < 2000) o = f2bf(e[m]*inv);
    wbf[(size_t)b*2016+m] = o;
  }
}

// ---------------- deconv0 (MFMA): 64->64, k3 s2 p0, 6->13; out: G0CL [b][169][64] raw bf16 ----------------
__global__ __launch_bounds__(256) void k_deconv0m(
    const float* __restrict__ zh, const ushort_t* __restrict__ WPK, const float* __restrict__ b0g,
    float* __restrict__ hdr, ushort_t* __restrict__ out){
  __shared__ ushort_t inp[64*64];      // [cell 8x8 halo][ci64], chunk-swizzled
  const int b = blockIdx.x, tid = threadIdx.x;
  // zero the halo tile (8 KB = 512 uint4)
  for (int i = tid; i < 512; i += 256) ((uint4*)inp)[i] = make_uint4(0,0,0,0);
  __syncthreads();
  // coalesced partial-sum read: 2304 floats = 576 f32x4 groups (36%4==0 -> group stays in one ci)
  for (int i = tid; i < 576; i += 256){
    int idx = i*4;
    f32x4 v = *(const f32x4*)&zh[(size_t)b*2304 + idx];
    #pragma unroll
    for (int j=1;j<NSPLB;j++)
      v += *(const f32x4*)&zh[(size_t)b*2304 + idx + (size_t)j*ZHSTRIDE];
    int ci = idx/36;
    int p  = idx - ci*36;
    int chunk = ci >> 3, cil = ci & 7;
    #pragma unroll
    for (int e2=0;e2<4;e2++){
      int pp = p + e2;
      int r6 = pp/6, c6 = pp - r6*6;
      int cell = (r6+1)*8 + (c6+1);
      int slot = chunk ^ ((cell>>1)&7);
      inp[cell*64 + slot*8 + cil] = f2bf(v[e2]);
    }
  }
  __syncthreads();
  const int wv = tid>>6, lane = tid&63, r = lane&15, q = lane>>4;
  float biasr[4];
  #pragma unroll
  for (int v=0;v<4;v++) biasr[v] = b0g[wv*16 + q*4 + v];
  const int NCOL[4]={7,6,7,6}, NPOS[4]={49,42,42,36}, NT[4]={4,3,3,3},
            NCH[4]={8,4,4,2}, KB[4]={0,16384,24576,32768}, KK[4]={256,128,128,64},
            PI[4]={0,0,1,1}, PJ[4]={0,1,0,1};
  const int TOFF[4][4] = {{9,8,1,0},{9,1,0,0},{9,8,0,0},{9,0,0,0}};
  float sacc[4]={0,0,0,0}, qacc[4]={0,0,0,0};
  #pragma unroll
  for (int cl=0; cl<4; cl++){
    bf16x8 af[8];
    #pragma unroll
    for (int m=0;m<NCH[cl];m++)
      af[m] = *(const bf16x8*)(WPK + OD0 + KB[cl] + (wv*16+r)*KK[cl] + m*32 + q*8);
    for (int t = 0; t < NT[cl]; t++){
      int p = t*16 + r;
      bool ok = p < NPOS[cl];
      int pc = ok ? p : 0;
      int a_ = pc/NCOL[cl], c_ = pc - a_*NCOL[cl];
      int pb = a_*8 + c_;
      f32x4 acc = {0.f,0.f,0.f,0.f};
      #pragma unroll
      for (int m=0;m<NCH[cl];m++){
        int cell = pb + TOFF[cl][m>>1];
        int chunk = (m&1)*4 + q;
        int slot = chunk ^ ((cell>>1)&7);
        bf16x8 bv = *(const bf16x8*)&inp[cell*64 + slot*8];
        acc = __builtin_amdgcn_mfma_f32_16x16x32_bf16(af[m], bv, acc, 0, 0, 0);
      }
      if (ok){
        int pos = (2*a_+PI[cl])*13 + (2*c_+PJ[cl]);
        ushort_t pk[4];
        #pragma unroll
        for (int reg=0;reg<4;reg++){
          float y = acc[reg] + biasr[reg];
          pk[reg] = f2bf(y);
          sacc[reg] += y; qacc[reg] += y*y;
        }
        *(uint2*)&out[((size_t)b*169 + pos)*64 + wv*16 + q*4] =
          make_uint2((uint32_t)pk[0] | ((uint32_t)pk[1]<<16), (uint32_t)pk[2] | ((uint32_t)pk[3]<<16));
      }
    }
  }
  float* bk = bkt(hdr, b);
  #pragma unroll
  for (int reg=0;reg<4;reg++){
    float s = sacc[reg], qq = qacc[reg];
    for (int o=8;o;o>>=1){ s += __shfl_down(s,o,16); qq += __shfl_down(qq,o,16); }
    if (r==0){ atomicAdd(&bk[H_DS0+wv*16+q*4+reg], s); atomicAdd(&bk[H_DQ0+wv*16+q*4+reg], qq); }
  }
}

// ---------------- deconv1 (MFMA): 64->32, k3 s2 p1, 13->25; 2 class-halves per image, grid 1024 ----------------
__global__ __launch_bounds__(256) void k_deconv1m(
    const ushort_t* __restrict__ g0, const ushort_t* __restrict__ WPK, const float* __restrict__ b1g,
    const float* __restrict__ g, const float* __restrict__ be,
    float* __restrict__ hdr, ushort_t* __restrict__ out){
  __shared__ ushort_t inp[169*64];     // [cell 13x13][ci64], chunk-swizzled (full tile)
  __shared__ float ac[128];
  const int blk = blockIdx.x, b = blk>>1, h = blk&1, tid = threadIdx.x;
  coef_lds(hdr, H_DS0, H_DQ0, g, be, ac, 64, 1.f/(512.f*169.f), tid);
  __syncthreads();
  for (int e = tid; e < 169*8; e += 256){
    int cell = e>>3, ch = e&7;
    uint4 raw = *(const uint4*)&g0[((size_t)b*169 + cell)*64 + ch*8];
    uint4 val = stage_chunk(raw, ac, ch*8, 64);
    int slot = ch ^ ((cell>>1)&7);
    *(uint4*)&inp[cell*64 + slot*8] = val;
  }
  __syncthreads();
  const int wv = tid>>6, lane = tid&63, r = lane&15, q = lane>>4;
  const int cotile = wv&1, ph = wv>>1;
  float biasr[4];
  #pragma unroll
  for (int v=0;v<4;v++) biasr[v] = b1g[cotile*16 + q*4 + v];
  const int NCOL[4]={13,12,13,12}, NPOS[4]={169,156,156,144}, NT[4]={11,10,10,9},
            NCH[4]={2,4,4,8}, KB[4]={0,2048,6144,10240}, KK[4]={64,128,128,256},
            PI[4]={0,0,1,1}, PJ[4]={0,1,0,1};
  const int TOFF[4][4] = {{0,0,0,0},{1,0,0,0},{13,0,0,0},{14,13,1,0}};
  float sacc[4]={0,0,0,0}, qacc[4]={0,0,0,0};
  #pragma unroll
  for (int cc=0; cc<2; cc++){
    const int cl = 2*h + cc;           // this half owns classes 2h, 2h+1
    bf16x8 af[8];
    #pragma unroll
    for (int m=0;m<8;m++)
      if (m < NCH[cl])
        af[m] = *(const bf16x8*)(WPK + OD1 + KB[cl] + (cotile*16+r)*KK[cl] + m*32 + q*8);
    for (int t = ph; t < NT[cl]; t += 2){
      int p = t*16 + r;
      bool ok = p < NPOS[cl];
      int pc = ok ? p : 0;
      int a_ = pc/NCOL[cl], c_ = pc - a_*NCOL[cl];
      int pb = a_*13 + c_;
      f32x4 acc = {0.f,0.f,0.f,0.f};
      for (int m=0;m<NCH[cl];m++){
        int cell = pb + TOFF[cl][m>>1];
        int chunk = (m&1)*4 + q;
        int slot = chunk ^ ((cell>>1)&7);
        bf16x8 bv = *(const bf16x8*)&inp[cell*64 + slot*8];
        acc = __builtin_amdgcn_mfma_f32_16x16x32_bf16(af[m], bv, acc, 0, 0, 0);
      }
      if (ok){
        int pos = (2*a_+PI[cl])*25 + (2*c_+PJ[cl]);
        ushort_t pk[4];
        #pragma unroll
        for (int reg=0;reg<4;reg++){
          float y = acc[reg] + biasr[reg];
          pk[reg] = f2bf(y);
          sacc[reg] += y; qacc[reg] += y*y;
        }
        *(uint2*)&out[((size_t)b*625 + pos)*32 + cotile*16 + q*4] =
          make_uint2((uint32_t)pk[0] | ((uint32_t)pk[1]<<16), (uint32_t)pk[2] | ((uint32_t)pk[3]<<16));
      }
    }
  }
  float* bk = bkt(hdr, blk);
  #pragma unroll
  for (int reg=0;reg<4;reg++){
    float s = sacc[reg], qq = qacc[reg];
    for (int o=8;o;o>>=1){ s += __shfl_down(s,o,16); qq += __shfl_down(qq,o,16); }
    if (r==0){ atomicAdd(&bk[H_DS1+cotile*16+q*4+reg], s); atomicAdd(&bk[H_DQ1+cotile*16+q*4+reg], qq); }
  }
}

// ---------------- deconv2 (MFMA): 32->16, k2 s2 p1 op1, 25->49; 2 class-halves per image, grid 1024 ----------------
__global__ __launch_bounds__(256) void k_deconv2m(
    const ushort_t* __restrict__ g1, const ushort_t* __restrict__ WPK, const float* __restrict__ bg,
    const float* __restrict__ g, const float* __restrict__ be,
    float* __restrict__ hdr, ushort_t* __restrict__ out){
  __shared__ ushort_t inp[625*32];     // [cell 25x25][ci32], chunk-swizzled (full tile)
  __shared__ float ac[64];
  const int blk = blockIdx.x, b = blk>>1, h = blk&1, tid = threadIdx.x;
  coef_lds(hdr, H_DS1, H_DQ1, g, be, ac, 32, 1.f/(512.f*625.f), tid);
  __syncthreads();
  for (int e = tid; e < 625*4; e += 256){
    int cell = e>>2, ch = e&3;
    uint4 raw = *(const uint4*)&g1[((size_t)b*625 + cell)*32 + ch*8];
    uint4 val = stage_chunk(raw, ac, ch*8, 32);
    int slot = ch ^ ((cell>>1)&3);
    *(uint4*)&inp[cell*32 + slot*8] = val;
  }
  __syncthreads();
  const int wv = tid>>6, lane = tid&63, r = lane&15, q = lane>>4;
  const int cl = 2*h + (wv>>1);        // this half owns classes 2h, 2h+1; 2 waves per class
  const int ph = wv&1;
  float biasr[4];
  #pragma unroll
  for (int v=0;v<4;v++) biasr[v] = bg[q*4 + v];
  const int NCOL[4]={25,24,25,24}, NPOS[4]={625,600,600,576}, NT[4]={40,38,38,36},
            TOFF[4]={0,1,25,26};
  const int nc = NCOL[cl], npos = NPOS[cl], nt = NT[cl], toff = TOFF[cl];
  bf16x8 af = *(const bf16x8*)(WPK + OD2 + cl*512 + r*32 + q*8);
  float sacc[4]={0,0,0,0}, qacc[4]={0,0,0,0};
  for (int t = ph; t < nt; t += 2){
    int p = t*16 + r;
    bool ok = p < npos;
    int pc = ok ? p : 0;
    int a_ = pc/nc, c_ = pc - a_*nc;
    int cell = a_*25 + c_ + toff;
    int slot = q ^ ((cell>>1)&3);
    f32x4 acc = {0.f,0.f,0.f,0.f};
    bf16x8 bv = *(const bf16x8*)&inp[cell*32 + slot*8];
    acc = __builtin_amdgcn_mfma_f32_16x16x32_bf16(af, bv, acc, 0, 0, 0);
    if (ok){
      ushort_t pk[4];
      #pragma unroll
      for (int reg=0;reg<4;reg++){
        float y = acc[reg] + biasr[reg];
        pk[reg] = f2bf(y);
        sacc[reg] += y; qacc[reg] += y*y;
      }
      *(uint2*)&out[(((size_t)b*4 + cl)*625 + p)*16 + q*4] =
        make_uint2((uint32_t)pk[0] | ((uint32_t)pk[1]<<16), (uint32_t)pk[2] | ((uint32_t)pk[3]<<16));
    }
  }
  float* bk = bkt(hdr, blk);
  #pragma unroll
  for (int reg=0;reg<4;reg++){
    float s = sacc[reg], qq = qacc[reg];
    for (int o=8;o;o>>=1){ s += __shfl_down(s,o,16); qq += __shfl_down(qq,o,16); }
    if (r==0){ atomicAdd(&bk[H_DS2+q*4+reg], s); atomicAdd(&bk[H_DQ2+q*4+reg], qq); }
  }
}

// ---------------- deconv3: input-location-per-thread; G2BF channel-last -> 2x uint4 loads ----------------
__global__ __launch_bounds__(256) void k_deconv3(const ushort_t* __restrict__ g2, const float* __restrict__ w,
                                                 const float* __restrict__ bias,
                                                 const float* __restrict__ g, const float* __restrict__ be,
                                                 float* __restrict__ hdr, float* __restrict__ out){
  __shared__ float ac[32];
  __shared__ float wl[64];
  const int tid = threadIdx.x;
  coef_lds(hdr, H_DS2, H_DQ2, g, be, ac, 16, 1.f/(512.f*2401.f), tid);
  if (tid >= 64 && tid < 128) wl[tid-64] = w[tid-64];
  __syncthreads();
  int idx = blockIdx.x*256 + tid;
  if (idx >= 512*2401) return;
  int b = idx / 2401; int loc = idx - b*2401;
  int ii = loc / 49, jj = loc - ii*49;
  int pi = ii & 1, pj = jj & 1, cl = pi*2 + pj;
  int a = ii >> 1, c = jj >> 1;
  int nc = pj ? 24 : 25;
  const float b0 = bias[0];
  float acc00 = b0, acc01 = b0, acc10 = b0, acc11 = b0;
  const ushort_t* gp = g2 + (((size_t)b*4 + cl)*625 + a*nc + c)*16;
  ushort_t rv[16];
  *(uint4*)&rv[0] = *(const uint4*)(gp);
  *(uint4*)&rv[8] = *(const uint4*)(gp + 8);
  #pragma unroll
  for (int ci=0; ci<16; ci++){
    float raw = bf2f(rv[ci]);
    float h = fmaxf(fmaf(ac[ci], raw, ac[16+ci]), 0.f);
    acc00 = fmaf(h, wl[ci*4+0], acc00);
    acc01 = fmaf(h, wl[ci*4+1], acc01);
    acc10 = fmaf(h, wl[ci*4+2], acc10);
    acc11 = fmaf(h, wl[ci*4+3], acc11);
  }
  float* op = out + (size_t)b*9604 + (2*ii)*98 + 2*jj;
  op[0]   = 1.f/(1.f + __expf(-acc00));
  op[1]   = 1.f/(1.f + __expf(-acc01));
  op[98]  = 1.f/(1.f + __expf(-acc10));
  op[99]  = 1.f/(1.f + __expf(-acc11));
}

// ======================================================================
extern "C" void kernel_launch(void* const* d_in, const int* in_sizes, int n_in,
                              void* d_out, int out_size, void* d_ws, size_t ws_size,
                              hipStream_t stream){
  (void)in_sizes; (void)n_in; (void)out_size; (void)ws_size;
  const float* x     = (const float*)d_in[0];
  const float* c1w   = (const float*)d_in[1];
  const float* c1b   = (const float*)d_in[2];
  const float* bn1g  = (const float*)d_in[3];
  const float* bn1b  = (const float*)d_in[4];
  const float* c2w   = (const float*)d_in[5];
  const float* c2b   = (const float*)d_in[6];
  const float* bn2g  = (const float*)d_in[7];
  const float* bn2b  = (const float*)d_in[8];
  const float* c3w   = (const float*)d_in[9];
  const float* c3b   = (const float*)d_in[10];
  const float* bn3g  = (const float*)d_in[11];
  const float* bn3b  = (const float*)d_in[12];
  const float* c4w   = (const float*)d_in[13];
  const float* c4b   = (const float*)d_in[14];
  const float* bn4g  = (const float*)d_in[15];
  const float* bn4b  = (const float*)d_in[16];
  const float* mem   = (const float*)d_in[17];
  const float* d0w   = (const float*)d_in[18];
  const float* d0b   = (const float*)d_in[19];
  const float* dbn0g = (const float*)d_in[20];
  const float* dbn0b = (const float*)d_in[21];
  const float* d1w   = (const float*)d_in[22];
  const float* d1b   = (const float*)d_in[23];
  const float* dbn1g = (const float*)d_in[24];
  const float* dbn1b = (const float*)d_in[25];
  const float* d2w   = (const float*)d_in[26];
  const float* d2b   = (const float*)d_in[27];
  const float* dbn2g = (const float*)d_in[28];
  const float* dbn2b = (const float*)d_in[29];
  const float* d3w   = (const float*)d_in[30];
  const float* d3b   = (const float*)d_in[31];

  float* hdr  = (float*)d_ws;
  float* H2f  = hdr + HDR_FLOATS;        // slot: H2CL bf16 (10.24M ushort) / later G1CL
  float* H3f  = H2f + 10240000;          // slot: H3CL bf16 (5.54M ushort) / later G0CL
  float* ZRAW = H3f + 5537792;           // 512*2304 fp32
  float* WSLOT= ZRAW + 1179648;          // 73728 floats (holds WPK bf16)
  float* G2   = WSLOT + 73728;           // 19.67M floats scratch region
  ushort_t* MEMBF = (ushort_t*)(G2 + 19668992); // 2000*2304
  ushort_t* MEMT  = MEMBF + 4608000;            // 2304*2016
  ushort_t* ZBF   = MEMT + 4644864;             // 512*2304 (unused this rev)
  ushort_t* WBF   = ZBF + 1179648;              // 512*2016
  ushort_t* WPK   = (ushort_t*)WSLOT;
  float* SIMP = G2;                      // NSPLA * 512*2000 = 8.19M floats
  float* ZHP  = G2 + (size_t)NSPLA*SIMSTRIDE;   // NSPLB * 512*2304 = 8.26M floats
  ushort_t* G2BF = (ushort_t*)G2;        // 512*4*625*16 bf16 (SIMP/ZHP dead by then)
  ushort_t* H2CL = (ushort_t*)H2f;
  ushort_t* H3CL = (ushort_t*)H3f;
  ushort_t* G0CL = (ushort_t*)H3f;       // reuse (H3CL dead after conv4m)
  ushort_t* G1CL = (ushort_t*)H2f;       // reuse (H2CL dead after conv3m)
  float* OUT = (float*)d_out;

  hipMemsetAsync(hdr, 0, HDR_FLOATS*sizeof(float), stream);
  k_prep     <<<PREP_TOT, 256, 0, stream>>>(mem, MEMBF, MEMT, hdr,
                                            c2w, c3w, c4w, d0w, d1w, d2w, WPK, x);
  k_conv2m   <<<1024, 256, 0, stream>>>(x, WPK, c2b, c1w, c1b, bn1g, bn1b, hdr, H2CL);
  k_conv3m   <<<1024, 256, 0, stream>>>(H2CL, WPK, c3b, bn2g, bn2b, hdr, H3CL);
  k_conv4m   <<<1024, 256, 0, stream>>>(H3CL, WPK, c4b, bn3g, bn3b, hdr, ZRAW);
  k_gemmA    <<<512, 256, 0, stream>>>(ZRAW, MEMBF, SIMP, bn4g, bn4b, hdr);
  k_softmax  <<<512, 256, 0, stream>>>(SIMP, hdr, WBF);
  k_gemmB    <<<504, 256, 0, stream>>>(WBF, MEMT, ZHP, 18, 2304, 2016, 63, 72, 9, ZHSTRIDE);
  k_deconv0m <<<512, 256, 0, stream>>>(ZHP, WPK, d0b, hdr, G0CL);
  k_deconv1m <<<1024, 256, 0, stream>>>(G0CL, WPK, d1b, dbn0g, dbn0b, hdr, G1CL);
  k_deconv2m <<<1024, 256, 0, stream>>>(G1CL, WPK, d2b, dbn1g, dbn1b, hdr, G2BF);
  k_deconv3  <<<4802, 256, 0, stream>>>(G2BF, d3w, d3b, dbn2g, dbn2b, hdr, OUT);
}

// Round 10
// 331.340 us; speedup vs baseline: 2.2597x; 2.2597x over previous
//
#include <hip/hip_runtime.h>
#include <stdint.h>

// R17: fix R16's deconv1m scratch-spill (runtime-indexed af[] -> local memory, 454us kernel).
// Compile-time class dispatch via template<int CL>; h-split kept (grid 1024).
// conv4m / deconv2m x2 splits from R16 kept (statically indexed, unaffected).

typedef unsigned short ushort_t;
typedef __bf16 bf16x8 __attribute__((ext_vector_type(8)));
typedef float f32x4 __attribute__((ext_vector_type(4)));

#define DEV static __device__ __forceinline__

DEV ushort_t f2bf(float f){
  union { float f; uint32_t u; } v; v.f = f;
  return (ushort_t)((v.u + 0x7FFFu + ((v.u >> 16) & 1u)) >> 16);
}
DEV float bf2f(ushort_t u){
  union { uint32_t u; float f; } v; v.u = ((uint32_t)u) << 16;
  return v.f;
}

// affine+relu two packed bf16 (raw) -> packed bf16
DEV uint32_t affine2(uint32_t rw, const float* ac, int ci, int nch){
  float lo = bf2f((ushort_t)(rw & 0xffffu));
  float hi = bf2f((ushort_t)(rw >> 16));
  lo = fmaxf(fmaf(ac[ci],   lo, ac[nch+ci]),   0.f);
  hi = fmaxf(fmaf(ac[ci+1], hi, ac[nch+ci+1]), 0.f);
  return (uint32_t)f2bf(lo) | ((uint32_t)f2bf(hi) << 16);
}
DEV uint4 stage_chunk(uint4 raw, const float* ac, int ci0, int nch){
  uint4 o;
  o.x = affine2(raw.x, ac, ci0+0, nch);
  o.y = affine2(raw.y, ac, ci0+2, nch);
  o.z = affine2(raw.z, ac, ci0+4, nch);
  o.w = affine2(raw.w, ac, ci0+6, nch);
  return o;
}

// ---------------- header (stats/coeff) offsets in floats ----------------
#define H_XS   0
#define H_S2   64
#define H_Q2   96
#define H_S3   192
#define H_Q3   256
#define H_S4   448
#define H_Q4   512
#define H_DS0  704
#define H_DQ0  768
#define H_DS1  960
#define H_DQ1  992
#define H_DS2  1088
#define H_DQ2  1104
#define H_ZN   1152   // [512]  sum of z^2 per row (softmax takes sqrtf)
#define H_MN   1664   // [2000] sum of mem^2 per row (softmax takes sqrtf)
#define H_BUK  4096   // 16 bucket banks of 1280 floats each
#define NBUK   16
#define BSTRIDE 1280
#define HDR_FLOATS (H_BUK + NBUK*BSTRIDE)

// packed-weight (bf16) offsets in WPK
#define OW2 0        // [32][160]  k=tap*16+ci, taps 0..9 (tap9 = zero pad)
#define OW3 5120     // [64][288]  k=tap*32+ci
#define OW4 23552    // [64][576]  k=tap*64+ci
#define OD0 60416    // 4 classes [64][K], K={256,128,128,64}
#define OD1 97280    // 4 classes [32][K], K={64,128,128,256}
#define OD2 115712   // 4 classes [16][32]
#define NWPK 117760

#define SIMSTRIDE 1024000   // 512*2000
#define ZHSTRIDE  1179648   // 512*2304
#define NSPLA 8             // split-K partials for GEMM1 (512 blocks)
#define NSPLB 7             // split-K partials for GEMM2 (504 blocks)

// k_prep block ranges: xstats, wprep, mem tiles (32m x 128f)
#define PREP_XS 256
#define PREP_W2 (PREP_XS + 460)      // 460*256 >= NWPK
#define PREP_TOT (PREP_W2 + 63*18)   // 63 mtiles * 18 ftiles = 1134

DEV float* bkt(float* hdr, int blk){ return hdr + H_BUK + (size_t)(blk & (NBUK-1))*BSTRIDE; }

DEV void coef_lds(const float* __restrict__ hdr, int offS, int offQ,
                  const float* __restrict__ g, const float* __restrict__ be,
                  float* ac, int nch, float invN, int tid){
  if (tid < nch){
    float s = 0.f, q = 0.f;
    #pragma unroll
    for (int k=0;k<NBUK;k++){
      s += hdr[H_BUK + k*BSTRIDE + offS + tid];
      q += hdr[H_BUK + k*BSTRIDE + offQ + tid];
    }
    float m = s*invN;
    float v = q*invN - m*m;
    float a = g[tid]*rsqrtf(v + 1e-5f);
    ac[tid] = a;
    ac[nch+tid] = be[tid] - m*a;
  }
}

// ---------------- fused prep: xstats, wprep, mem tiles (bf16 + transpose + norms) ----------------
__global__ __launch_bounds__(256) void k_prep(
    const float* __restrict__ mem, ushort_t* __restrict__ mbf, ushort_t* __restrict__ mt,
    float* __restrict__ hdr,
    const float* __restrict__ c2w, const float* __restrict__ c3w, const float* __restrict__ c4w,
    const float* __restrict__ d0w, const float* __restrict__ d1w, const float* __restrict__ d2w,
    ushort_t* __restrict__ WPK, const float* __restrict__ x){
  __shared__ ushort_t smu[32*132];    // mem branch: bf16 tile [32m][128f +4 pad]; xstats: 8 floats
  const int blk = blockIdx.x, tid = threadIdx.x;
  if (blk < PREP_XS){
    // xstats: strided-sampled input stats for bn1 fold (256 blocks, grid-stride)
    float* sm = (float*)smu;
    float s = 0.f, q = 0.f;
    const int total = 512*49*49;
    for (int idx = blk*256 + tid; idx < total; idx += 256*256){
      int b = idx / 2401;
      int r = idx - b*2401;
      int i = r / 49, j = r - i*49;
      float v = 0.f;
      if (i > 0 && j > 0) v = x[(size_t)b*9216 + (2*i-1)*96 + (2*j-1)];
      s += v; q += v*v;
    }
    for (int o=32;o;o>>=1){ s += __shfl_down(s,o,64); q += __shfl_down(q,o,64); }
    int w = tid>>6;
    if ((tid&63)==0){ sm[w*2]=s; sm[w*2+1]=q; }
    __syncthreads();
    if (tid==0){
      float* bk = bkt(hdr, blk);
      atomicAdd(&bk[H_XS+0], sm[0]+sm[2]+sm[4]+sm[6]);
      atomicAdd(&bk[H_XS+1], sm[1]+sm[3]+sm[5]+sm[7]);
    }
  } else if (blk < PREP_W2){
    // weight pack
    int i = (blk - PREP_XS)*256 + tid;
    if (i >= NWPK) return;
    float val = 0.f;
    if (i < OW3){                       // conv2 [32][160]
      int co = i/160, k = i - co*160, tap = k>>4, ci = k&15;
      if (tap < 9) val = c2w[(co*16+ci)*9+tap];
    } else if (i < OW4){                // conv3 [64][288]
      int r = i - OW3; int co = r/288, k = r - co*288, tap = k>>5, ci = k&31;
      val = c3w[(co*32+ci)*9+tap];
    } else if (i < OD0){                // conv4 [64][576]
      int r = i - OW4; int co = r/576, k = r - co*576, tap = k>>6, ci = k&63;
      val = c4w[(co*64+ci)*9+tap];
    } else if (i < OD1){                // deconv0 classes
      int r = i - OD0;
      const int base[4]={0,16384,24576,32768}, K[4]={256,128,128,64};
      const int T0[4][4] = {{0,2,6,8},{1,7,0,0},{3,5,0,0},{4,0,0,0}};
      int cl = (r<16384)?0:(r<24576)?1:(r<32768)?2:3;
      int rr = r - base[cl]; int co = rr/K[cl], k = rr - co*K[cl], t = k>>6, ci = k&63;
      val = d0w[(ci*64+co)*9 + T0[cl][t]];
    } else if (i < OD2){                // deconv1 classes
      int r = i - OD1;
      const int base[4]={0,2048,6144,10240}, K[4]={64,128,128,256};
      const int T1[4][4] = {{4,0,0,0},{3,5,0,0},{1,7,0,0},{0,2,6,8}};
      int cl = (r<2048)?0:(r<6144)?1:(r<10240)?2:3;
      int rr = r - base[cl]; int co = rr/K[cl], k = rr - co*K[cl], t = k>>6, ci = k&63;
      val = d1w[(ci*32+co)*9 + T1[cl][t]];
    } else {                            // deconv2 classes [4][16][32]
      int r = i - OD2;
      int cl = r>>9, s = r&511, co = s>>5, ci = s&31;
      const int pis[4]={0,0,1,1}, pjs[4]={0,1,0,1};
      val = d2w[((ci*16+co)*2 + (1-pis[cl]))*2 + (1-pjs[cl])];
    }
    WPK[i] = f2bf(val);
  } else {
    // 32m x 128f tile of memory: f32x4 read once, write MEMBF (uint2) + MEMT + norm^2 partials
    const int mb = blk - PREP_W2;
    const int ft = mb % 18, mtile = mb / 18;
    const int tx = tid & 31, ty = tid >> 5;
    #pragma unroll
    for (int r0=0;r0<4;r0++){
      int m = mtile*32 + r0*8 + ty;
      int f = ft*128 + tx*4;
      f32x4 v = {0.f,0.f,0.f,0.f};
      if (m < 2000) v = *(const f32x4*)&mem[(size_t)m*2304 + f];
      ushort_t h0=f2bf(v[0]), h1=f2bf(v[1]), h2=f2bf(v[2]), h3=f2bf(v[3]);
      uint2 pk = make_uint2((uint32_t)h0 | ((uint32_t)h1<<16), (uint32_t)h2 | ((uint32_t)h3<<16));
      *(uint2*)&smu[(r0*8+ty)*132 + tx*4] = pk;
      if (m < 2000) *(uint2*)&mbf[(size_t)m*2304 + f] = pk;
      float p = v[0]*v[0] + v[1]*v[1] + v[2]*v[2] + v[3]*v[3];
      for (int o=16;o;o>>=1) p += __shfl_down(p, o, 32);
      if (tx==0 && m<2000) atomicAdd(&hdr[H_MN+m], p);
    }
    __syncthreads();
    #pragma unroll
    for (int ff=0; ff<16; ff++){
      int fl = ff*8 + ty;
      mt[(size_t)(ft*128 + fl)*2016 + mtile*32 + tx] = smu[tx*132 + fl];
    }
  }
}

// ---------------- conv2 (MFMA): 16->32, 3x3 s2 p1; writes H2CL [b][625][32] raw bf16 ----------------
__global__ __launch_bounds__(256) void k_conv2m(
    const float* __restrict__ x, const ushort_t* __restrict__ WPK, const float* __restrict__ b2g,
    const float* __restrict__ c1w, const float* __restrict__ c1b,
    const float* __restrict__ bn1g, const float* __restrict__ bn1b,
    float* __restrict__ hdr, ushort_t* __restrict__ out){
  __shared__ ushort_t inp[27*51*16];    // [row][col][ci16], halo'd 51-grid rows [2*ro..2*ro+26]
  __shared__ float ac[32];
  const int blk = blockIdx.x, b = blk>>1, h = blk&1, tid = threadIdx.x;
  const int ro = h*13, nr = h?12:13, npos = nr*25, ntiles = (npos+15)>>4;
  if (tid < 16){
    float sx=0.f, qx=0.f;
    #pragma unroll
    for (int k=0;k<NBUK;k++){ sx += hdr[H_BUK+k*BSTRIDE+H_XS]; qx += hdr[H_BUK+k*BSTRIDE+H_XS+1]; }
    const float N = 512.f*49.f*49.f;
    float mx = sx/N, vx = qx/N - mx*mx;
    float mean = c1w[tid]*mx + c1b[tid];
    float a = bn1g[tid]*rsqrtf(c1w[tid]*c1w[tid]*vx + 1e-5f);
    ac[tid] = a*c1w[tid];
    ac[16+tid] = a*(c1b[tid]-mean) + bn1b[tid];
  }
  __syncthreads();
  for (int e = tid; e < 27*51; e += 256){
    int lr = e/51, gc = e - lr*51;
    int grg = 2*ro + lr;
    bool inside = (grg>=1 && grg<=49 && gc>=1 && gc<=49);
    float v = 0.f;
    if (grg>=2 && grg<=49 && gc>=2 && gc<=49) v = x[(size_t)b*9216 + (2*grg-3)*96 + (2*gc-3)];
    ushort_t hv[16];
    if (inside){
      #pragma unroll
      for (int c=0;c<16;c++) hv[c] = f2bf(fmaxf(fmaf(ac[c], v, ac[16+c]), 0.f));
    } else {
      #pragma unroll
      for (int c=0;c<16;c++) hv[c] = 0;
    }
    uint32_t w0[8];
    #pragma unroll
    for (int c=0;c<8;c++) w0[c] = (uint32_t)hv[2*c] | ((uint32_t)hv[2*c+1]<<16);
    uint4* dst = (uint4*)&inp[e*16];
    dst[0] = make_uint4(w0[0],w0[1],w0[2],w0[3]);
    dst[1] = make_uint4(w0[4],w0[5],w0[6],w0[7]);
  }
  __syncthreads();
  const int wv = tid>>6, lane = tid&63, r = lane&15, q = lane>>4;
  const int cotile = wv&1;
  bf16x8 af[5];
  #pragma unroll
  for (int c=0;c<5;c++) af[c] = *(const bf16x8*)(WPK + OW2 + (cotile*16+r)*160 + c*32 + q*8);
  float biasr[4];
  #pragma unroll
  for (int v=0;v<4;v++) biasr[v] = b2g[cotile*16 + q*4 + v];
  const int TOFF[10] = {0,1,2,51,52,53,102,103,104,0};
  const int qhi = q>>1, ci0 = (q&1)*8;
  float sacc[4]={0,0,0,0}, qacc[4]={0,0,0,0};
  for (int t = wv>>1; t < ntiles; t += 2){
    int p = t*16 + r;
    bool ok = p < npos;
    int pc = ok ? p : 0;
    int a_ = pc/25, c_ = pc - a_*25;
    int pb = (2*a_)*51 + 2*c_;
    f32x4 acc = {0.f,0.f,0.f,0.f};
    #pragma unroll
    for (int c=0;c<5;c++){
      int toff = qhi ? TOFF[2*c+1] : TOFF[2*c];
      bf16x8 bv = *(const bf16x8*)&inp[(pb + toff)*16 + ci0];
      acc = __builtin_amdgcn_mfma_f32_16x16x32_bf16(af[c], bv, acc, 0, 0, 0);
    }
    if (ok){
      int pg = (ro + a_)*25 + c_;
      ushort_t pk[4];
      #pragma unroll
      for (int reg=0;reg<4;reg++){
        float y = acc[reg] + biasr[reg];
        pk[reg] = f2bf(y);
        sacc[reg] += y; qacc[reg] += y*y;
      }
      *(uint2*)&out[((size_t)b*625 + pg)*32 + cotile*16 + q*4] =
        make_uint2((uint32_t)pk[0] | ((uint32_t)pk[1]<<16), (uint32_t)pk[2] | ((uint32_t)pk[3]<<16));
    }
  }
  float* bk = bkt(hdr, blk);
  #pragma unroll
  for (int reg=0;reg<4;reg++){
    float s = sacc[reg], qq = qacc[reg];
    for (int o=8;o;o>>=1){ s += __shfl_down(s,o,16); qq += __shfl_down(qq,o,16); }
    if (r==0){ atomicAdd(&bk[H_S2+cotile*16+q*4+reg], s); atomicAdd(&bk[H_Q2+cotile*16+q*4+reg], qq); }
  }
}

// ---------------- conv3 (MFMA): 32->64, 3x3 s2 p1, 25->13; 2 spatial halves per image ----------------
__global__ __launch_bounds__(256) void k_conv3m(
    const ushort_t* __restrict__ h2, const ushort_t* __restrict__ WPK, const float* __restrict__ b3g,
    const float* __restrict__ g, const float* __restrict__ be,
    float* __restrict__ hdr, ushort_t* __restrict__ out){
  __shared__ ushort_t inp[15*27*32];   // [lr][lc][ci32], chunk-swizzled
  __shared__ float ac[64];
  const int blk = blockIdx.x, b = blk>>1, h = blk&1, tid = threadIdx.x;
  const int a0 = h*7, na = h?6:7, npos = na*13, ntiles = (npos+15)>>4, nrows = 2*na+1;
  coef_lds(hdr, H_S2, H_Q2, g, be, ac, 32, 1.f/(512.f*625.f), tid);
  __syncthreads();
  for (int e = tid; e < nrows*27*4; e += 256){
    int cell = e>>2, ch = e&3;
    int lr = cell/27, lc = cell - lr*27;
    int ii = 2*a0 - 1 + lr, j = lc - 1;
    uint4 val = make_uint4(0,0,0,0);
    if ((unsigned)ii < 25u && (unsigned)j < 25u){
      uint4 raw = *(const uint4*)&h2[((size_t)b*625 + ii*25 + j)*32 + ch*8];
      val = stage_chunk(raw, ac, ch*8, 32);
    }
    int slot = ch ^ ((cell>>1)&3);
    *(uint4*)&inp[cell*32 + slot*8] = val;
  }
  __syncthreads();
  const int wv = tid>>6, lane = tid&63, r = lane&15, q = lane>>4;
  bf16x8 af[9];
  #pragma unroll
  for (int c=0;c<9;c++) af[c] = *(const bf16x8*)(WPK + OW3 + (wv*16+r)*288 + c*32 + q*8);
  float biasr[4];
  #pragma unroll
  for (int v=0;v<4;v++) biasr[v] = b3g[wv*16 + q*4 + v];
  const int TOFF[9] = {0,1,2,27,28,29,54,55,56};
  float sacc[4]={0,0,0,0}, qacc[4]={0,0,0,0};
  for (int t = 0; t < ntiles; t++){
    int p = t*16 + r;
    bool ok = p < npos;
    int pc = ok ? p : 0;
    int a_ = pc/13, c_ = pc - a_*13;
    int pb = (2*a_)*27 + 2*c_;
    f32x4 acc = {0.f,0.f,0.f,0.f};
    #pragma unroll
    for (int c=0;c<9;c++){
      int cell = pb + TOFF[c];
      int slot = q ^ ((cell>>1)&3);
      bf16x8 bv = *(const bf16x8*)&inp[cell*32 + slot*8];
      acc = __builtin_amdgcn_mfma_f32_16x16x32_bf16(af[c], bv, acc, 0, 0, 0);
    }
    if (ok){
      int pos = (a0 + a_)*13 + c_;
      ushort_t pk[4];
      #pragma unroll
      for (int reg=0;reg<4;reg++){
        float y = acc[reg] + biasr[reg];
        pk[reg] = f2bf(y);
        sacc[reg] += y; qacc[reg] += y*y;
      }
      *(uint2*)&out[((size_t)b*169 + pos)*64 + wv*16 + q*4] =
        make_uint2((uint32_t)pk[0] | ((uint32_t)pk[1]<<16), (uint32_t)pk[2] | ((uint32_t)pk[3]<<16));
    }
  }
  float* bk = bkt(hdr, blk);
  #pragma unroll
  for (int reg=0;reg<4;reg++){
    float s = sacc[reg], qq = qacc[reg];
    for (int o=8;o;o>>=1){ s += __shfl_down(s,o,16); qq += __shfl_down(qq,o,16); }
    if (r==0){ atomicAdd(&bk[H_S3+wv*16+q*4+reg], s); atomicAdd(&bk[H_Q3+wv*16+q*4+reg], qq); }
  }
}

// ---------------- conv4 (MFMA): 64->64, 3x3 s2 p0, 13->6; 2 row-halves per image, grid 1024 ----------------
__global__ __launch_bounds__(256) void k_conv4m(
    const ushort_t* __restrict__ h3, const ushort_t* __restrict__ WPK, const float* __restrict__ b4g,
    const float* __restrict__ g, const float* __restrict__ be,
    float* __restrict__ hdr, float* __restrict__ out){
  __shared__ ushort_t inp[91*64];      // [7 rows x 13 cols][ci64], chunk-swizzled (local rows 6h..6h+6)
  __shared__ float ac[128];
  const int blk = blockIdx.x, b = blk>>1, h = blk&1, tid = threadIdx.x;
  coef_lds(hdr, H_S3, H_Q3, g, be, ac, 64, 1.f/(512.f*169.f), tid);
  __syncthreads();
  for (int e = tid; e < 91*8; e += 256){
    int cell = e>>3, ch = e&7;
    int lr = cell/13, lc = cell - lr*13;
    int gr = 6*h + lr;                  // global row 0..12
    uint4 raw = *(const uint4*)&h3[((size_t)b*169 + gr*13 + lc)*64 + ch*8];
    uint4 val = stage_chunk(raw, ac, ch*8, 64);
    int slot = ch ^ ((cell>>1)&7);
    *(uint4*)&inp[cell*64 + slot*8] = val;
  }
  __syncthreads();
  const int wv = tid>>6, lane = tid&63, r = lane&15, q = lane>>4;
  bf16x8 af[18];
  #pragma unroll
  for (int c=0;c<18;c++) af[c] = *(const bf16x8*)(WPK + OW4 + (wv*16+r)*576 + c*32 + q*8);
  float biasr[4];
  #pragma unroll
  for (int v=0;v<4;v++) biasr[v] = b4g[wv*16 + q*4 + v];
  const int TOFF[9] = {0,1,2,13,14,15,26,27,28};
  float sacc[4]={0,0,0,0}, qacc[4]={0,0,0,0};
  for (int t = 0; t < 2; t++){
    int p = t*16 + r;                   // local position in 18 (3 rows x 6 cols)
    bool ok = p < 18;
    int pc = ok ? p : 0;
    int la = pc/6, c_ = pc - la*6;      // la in [0,3)
    int a_ = 3*h + la;                  // global output row
    int pb = (2*la)*13 + 2*c_;          // local cell base
    f32x4 acc = {0.f,0.f,0.f,0.f};
    #pragma unroll
    for (int c=0;c<18;c++){
      int cell = pb + TOFF[c>>1];
      int chunk = (c&1)*4 + q;
      int slot = chunk ^ ((cell>>1)&7);
      bf16x8 bv = *(const bf16x8*)&inp[cell*64 + slot*8];
      acc = __builtin_amdgcn_mfma_f32_16x16x32_bf16(af[c], bv, acc, 0, 0, 0);
    }
    if (ok){
      int pg = a_*6 + c_;               // global position
      #pragma unroll
      for (int reg=0;reg<4;reg++){
        float y = acc[reg] + biasr[reg];
        out[((size_t)b*64 + wv*16 + q*4 + reg)*36 + pg] = y;
        sacc[reg] += y; qacc[reg] += y*y;
      }
    }
  }
  float* bk = bkt(hdr, blk);
  #pragma unroll
  for (int reg=0;reg<4;reg++){
    float s = sacc[reg], qq = qacc[reg];
    for (int o=8;o;o>>=1){ s += __shfl_down(s,o,16); qq += __shfl_down(qq,o,16); }
    if (r==0){ atomicAdd(&bk[H_S4+wv*16+q*4+reg], s); atomicAdd(&bk[H_Q4+wv*16+q*4+reg], qq); }
  }
}

// ---------------- GEMM1 with fused z = relu(bn4(ZRAW)) on A-stage + z-norm^2 atomics ----------------
__global__ __launch_bounds__(256) void k_gemmA(
    const float* __restrict__ ZR, const ushort_t* __restrict__ Bm, float* __restrict__ D,
    const float* __restrict__ g, const float* __restrict__ be, float* __restrict__ hdr){
  __shared__ __align__(16) ushort_t lB[128*40];
  __shared__ __align__(16) ushort_t lA[128*40];
  __shared__ float ac[128];
  const int blk = blockIdx.x;
  const int s = blk >> 6, t = blk & 63;          // 8 splits x 64 tiles = 512 blocks
  const int bi = t >> 4, bj = t & 15;
  const int m0 = bi*128, n0 = bj*128;
  const int k0 = s*9, k1 = k0 + 9;               // 72 k-steps / 8
  const int tid = threadIdx.x;
  coef_lds(hdr, H_S4, H_Q4, g, be, ac, 64, 1.f/(512.f*36.f), tid);
  const int lane = tid & 63, wv = tid >> 6;
  const int r = lane & 15, q = lane >> 4;
  const int wr = wv >> 1, wc = wv & 1;
  const bool bj0 = (bj == 0);
  float* Ds = D + (size_t)s*SIMSTRIDE;
  const int srow = tid >> 1, skq = (tid & 1) * 16;
  const bool bok = (n0 + srow) < 2000;
  const ushort_t* pb = Bm + (size_t)(n0 + srow)*2304 + skq;
  const float*    pa = ZR + (size_t)(m0 + srow)*2304 + skq;
  uint4* wB = (uint4*)&lB[srow*40 + skq];
  uint4* wA = (uint4*)&lA[srow*40 + skq];
  const uint4 zz = make_uint4(0,0,0,0);
  uint4 rb0 = bok ? *(const uint4*)(pb + (size_t)k0*32)     : zz;
  uint4 rb1 = bok ? *(const uint4*)(pb + (size_t)k0*32 + 8) : zz;
  f32x4 raA[4];
  #pragma unroll
  for (int i=0;i<4;i++) raA[i] = *(const f32x4*)(pa + (size_t)k0*32 + i*4);
  f32x4 acc[4][4];
  #pragma unroll
  for (int i=0;i<4;i++)
    #pragma unroll
    for (int j=0;j<4;j++) acc[i][j] = (f32x4){0.f,0.f,0.f,0.f};
  float zsq = 0.f;
  __syncthreads();   // ac ready
  for (int k=k0; k<k1; k++){
    if (k > k0) __syncthreads();
    wB[0] = rb0; wB[1] = rb1;
    {
      const int kb = k*32 + skq;
      uint32_t pw[8];
      #pragma unroll
      for (int jj=0;jj<8;jj++){
        float v0 = raA[jj>>1][(jj&1)*2+0];
        float v1 = raA[jj>>1][(jj&1)*2+1];
        int c0 = (kb + 2*jj) / 36;
        int c1 = (kb + 2*jj + 1) / 36;
        float h0 = fmaxf(fmaf(ac[c0], v0, ac[64+c0]), 0.f);
        float h1 = fmaxf(fmaf(ac[c1], v1, ac[64+c1]), 0.f);
        if (bj0) zsq += h0*h0 + h1*h1;
        pw[jj] = (uint32_t)f2bf(h0) | ((uint32_t)f2bf(h1) << 16);
      }
      wA[0] = make_uint4(pw[0],pw[1],pw[2],pw[3]);
      wA[1] = make_uint4(pw[4],pw[5],pw[6],pw[7]);
    }
    if (k+1 < k1){
      const ushort_t* nb = pb + (size_t)(k+1)*32;
      rb0 = bok ? *(const uint4*)(nb)     : zz;
      rb1 = bok ? *(const uint4*)(nb + 8) : zz;
      const float* na = pa + (size_t)(k+1)*32;
      #pragma unroll
      for (int i=0;i<4;i++) raA[i] = *(const f32x4*)(na + i*4);
    }
    __syncthreads();
    bf16x8 aF[4], bF[4];
    #pragma unroll
    for (int mt=0;mt<4;mt++) aF[mt] = *(const bf16x8*)&lA[(wr*64+mt*16+r)*40 + q*8];
    #pragma unroll
    for (int nt=0;nt<4;nt++) bF[nt] = *(const bf16x8*)&lB[(wc*64+nt*16+r)*40 + q*8];
    #pragma unroll
    for (int mt=0;mt<4;mt++)
      #pragma unroll
      for (int nt=0;nt<4;nt++)
        acc[mt][nt] = __builtin_amdgcn_mfma_f32_16x16x32_bf16(aF[mt], bF[nt], acc[mt][nt], 0, 0, 0);
  }
  if (bj0){
    zsq += __shfl_down(zsq, 1, 64);
    if ((tid & 1) == 0) atomicAdd(&hdr[H_ZN + m0 + srow], zsq);
  }
  #pragma unroll
  for (int mt=0;mt<4;mt++){
    int row = m0 + wr*64 + mt*16 + q*4;
    #pragma unroll
    for (int nt=0;nt<4;nt++){
      int col = n0 + wc*64 + nt*16 + r;
      if (col < 2000){
        #pragma unroll
        for (int reg=0;reg<4;reg++)
          Ds[(size_t)(row+reg)*2000 + col] = acc[mt][nt][reg];
      }
    }
  }
}

// ---------------- blocked GEMM, split-K (GEMM2) ----------------
__global__ __launch_bounds__(256) void k_gemmB(const ushort_t* __restrict__ A, const ushort_t* __restrict__ Bm,
                                               float* __restrict__ D, int Nb, int N, int Kp, int kch,
                                               int tiles, int ksp, size_t dstride){
  __shared__ __align__(16) ushort_t lB[128*40];
  const int blk = blockIdx.x;
  const int s = blk / tiles, t = blk - s*tiles;
  const int bi = t / Nb, bj = t - bi*Nb;
  const int m0 = bi*128, n0 = bj*128;
  const int k0 = s*ksp, k1 = min(kch, k0 + ksp);
  const int tid = threadIdx.x;
  const int lane = tid & 63, wv = tid >> 6;
  const int r = lane & 15, q = lane >> 4;
  const int wr = wv >> 1, wc = wv & 1;
  float* Ds = D + (size_t)s*dstride;
  const int srow = tid >> 1, skq = (tid & 1) * 16;
  const bool bok = (n0 + srow) < N;
  const ushort_t* pb = Bm + (size_t)(n0 + srow)*Kp + skq;
  uint4* wB = (uint4*)&lB[srow*40 + skq];
  const uint4 zz = make_uint4(0,0,0,0);
  uint4 rb0 = bok ? *(const uint4*)(pb + k0*32)     : zz;
  uint4 rb1 = bok ? *(const uint4*)(pb + k0*32 + 8) : zz;
  const ushort_t* pa = A + (size_t)(m0 + wr*64 + r)*Kp + q*8;
  bf16x8 aN[4];
  #pragma unroll
  for (int mt=0;mt<4;mt++) aN[mt] = *(const bf16x8*)(pa + k0*32 + (size_t)(mt*16)*Kp);
  f32x4 acc[4][4];
  #pragma unroll
  for (int i=0;i<4;i++)
    #pragma unroll
    for (int j=0;j<4;j++) acc[i][j] = (f32x4){0.f,0.f,0.f,0.f};
  for (int k=k0; k<k1; k++){
    if (k > k0) __syncthreads();
    wB[0] = rb0; wB[1] = rb1;
    bf16x8 aF[4];
    #pragma unroll
    for (int mt=0;mt<4;mt++) aF[mt] = aN[mt];
    if (k+1 < k1){
      const ushort_t* nb = pb + (k+1)*32;
      rb0 = bok ? *(const uint4*)(nb)     : zz;
      rb1 = bok ? *(const uint4*)(nb + 8) : zz;
      const ushort_t* na = pa + (k+1)*32;
      #pragma unroll
      for (int mt=0;mt<4;mt++) aN[mt] = *(const bf16x8*)(na + (size_t)(mt*16)*Kp);
    }
    __syncthreads();
    bf16x8 bF[4];
    #pragma unroll
    for (int nt=0;nt<4;nt++) bF[nt] = *(const bf16x8*)&lB[(wc*64+nt*16+r)*40 + q*8];
    #pragma unroll
    for (int mt=0;mt<4;mt++)
      #pragma unroll
      for (int nt=0;nt<4;nt++)
        acc[mt][nt] = __builtin_amdgcn_mfma_f32_16x16x32_bf16(aF[mt], bF[nt], acc[mt][nt], 0, 0, 0);
  }
  #pragma unroll
  for (int mt=0;mt<4;mt++){
    int row = m0 + wr*64 + mt*16 + q*4;
    #pragma unroll
    for (int nt=0;nt<4;nt++){
      int col = n0 + wc*64 + nt*16 + r;
      if (col < N){
        #pragma unroll
        for (int reg=0;reg<4;reg++)
          Ds[(size_t)(row+reg)*N + col] = acc[mt][nt][reg];
      }
    }
  }
}

// softmax over M=2000 (sums NSPLA split-K partials) + hard-shrink + L1 renorm -> bf16
__global__ __launch_bounds__(256) void k_softmax(const float* __restrict__ sim, float* __restrict__ hdr,
                                                 ushort_t* __restrict__ wbf){
  __shared__ float e[2000];
  __shared__ float red[8];
  const int b = blockIdx.x, tid = threadIdx.x;
  const float znb = sqrtf(hdr[H_ZN+b]);
  float part = 0.f;
  for (int m=tid;m<2000;m+=256){
    size_t ix = (size_t)b*2000+m;
    float sv = 0.f;
    #pragma unroll
    for (int j=0;j<NSPLA;j++) sv += sim[ix + (size_t)j*SIMSTRIDE];
    float mnb = sqrtf(hdr[H_MN+m]);
    float s = sv / fmaxf(znb * mnb, 1e-8f);
    float ev = __expf(s);
    e[m] = ev; part += ev;
  }
  for (int o=32;o;o>>=1) part += __shfl_down(part,o,64);
  if ((tid&63)==0) red[tid>>6] = part;
  __syncthreads();
  const float denom = red[0]+red[1]+red[2]+red[3];
  const float t = 1.0f/2000.0f;
  float part2 = 0.f;
  for (int m=tid;m<2000;m+=256){
    float w = e[m]/denom;
    float d = w - t;
    float sh = fmaxf(d,0.f)*w/(fabsf(d)+0.01f);
    e[m] = sh; part2 += sh;
  }
  for (int o=32;o;o>>=1) part2 += __shfl_down(part2,o,64);
  if ((tid&63)==0) red[4+(tid>>6)] = part2;
  __syncthreads();
  const float inv = 1.0f/(red[4]+red[5]+red[6]+red[7]);
  for (int m=tid;m<2016;m+=256){
    ushort_t o = 0;
    if (m < 2000) o = f2bf(e[m]*inv);
    wbf[(size_t)b*2016+m] = o;
  }
}

// ---------------- deconv0 (MFMA): 64->64, k3 s2 p0, 6->13; out: G0CL [b][169][64] raw bf16 ----------------
__global__ __launch_bounds__(256) void k_deconv0m(
    const float* __restrict__ zh, const ushort_t* __restrict__ WPK, const float* __restrict__ b0g,
    float* __restrict__ hdr, ushort_t* __restrict__ out){
  __shared__ ushort_t inp[64*64];      // [cell 8x8 halo][ci64], chunk-swizzled
  const int b = blockIdx.x, tid = threadIdx.x;
  for (int i = tid; i < 512; i += 256) ((uint4*)inp)[i] = make_uint4(0,0,0,0);
  __syncthreads();
  for (int i = tid; i < 576; i += 256){
    int idx = i*4;
    f32x4 v = *(const f32x4*)&zh[(size_t)b*2304 + idx];
    #pragma unroll
    for (int j=1;j<NSPLB;j++)
      v += *(const f32x4*)&zh[(size_t)b*2304 + idx + (size_t)j*ZHSTRIDE];
    int ci = idx/36;
    int p  = idx - ci*36;
    int chunk = ci >> 3, cil = ci & 7;
    #pragma unroll
    for (int e2=0;e2<4;e2++){
      int pp = p + e2;
      int r6 = pp/6, c6 = pp - r6*6;
      int cell = (r6+1)*8 + (c6+1);
      int slot = chunk ^ ((cell>>1)&7);
      inp[cell*64 + slot*8 + cil] = f2bf(v[e2]);
    }
  }
  __syncthreads();
  const int wv = tid>>6, lane = tid&63, r = lane&15, q = lane>>4;
  float biasr[4];
  #pragma unroll
  for (int v=0;v<4;v++) biasr[v] = b0g[wv*16 + q*4 + v];
  const int NCOL[4]={7,6,7,6}, NPOS[4]={49,42,42,36}, NT[4]={4,3,3,3},
            NCH[4]={8,4,4,2}, KB[4]={0,16384,24576,32768}, KK[4]={256,128,128,64},
            PI[4]={0,0,1,1}, PJ[4]={0,1,0,1};
  const int TOFF[4][4] = {{9,8,1,0},{9,1,0,0},{9,8,0,0},{9,0,0,0}};
  float sacc[4]={0,0,0,0}, qacc[4]={0,0,0,0};
  #pragma unroll
  for (int cl=0; cl<4; cl++){
    bf16x8 af[8];
    #pragma unroll
    for (int m=0;m<NCH[cl];m++)
      af[m] = *(const bf16x8*)(WPK + OD0 + KB[cl] + (wv*16+r)*KK[cl] + m*32 + q*8);
    for (int t = 0; t < NT[cl]; t++){
      int p = t*16 + r;
      bool ok = p < NPOS[cl];
      int pc = ok ? p : 0;
      int a_ = pc/NCOL[cl], c_ = pc - a_*NCOL[cl];
      int pb = a_*8 + c_;
      f32x4 acc = {0.f,0.f,0.f,0.f};
      #pragma unroll
      for (int m=0;m<NCH[cl];m++){
        int cell = pb + TOFF[cl][m>>1];
        int chunk = (m&1)*4 + q;
        int slot = chunk ^ ((cell>>1)&7);
        bf16x8 bv = *(const bf16x8*)&inp[cell*64 + slot*8];
        acc = __builtin_amdgcn_mfma_f32_16x16x32_bf16(af[m], bv, acc, 0, 0, 0);
      }
      if (ok){
        int pos = (2*a_+PI[cl])*13 + (2*c_+PJ[cl]);
        ushort_t pk[4];
        #pragma unroll
        for (int reg=0;reg<4;reg++){
          float y = acc[reg] + biasr[reg];
          pk[reg] = f2bf(y);
          sacc[reg] += y; qacc[reg] += y*y;
        }
        *(uint2*)&out[((size_t)b*169 + pos)*64 + wv*16 + q*4] =
          make_uint2((uint32_t)pk[0] | ((uint32_t)pk[1]<<16), (uint32_t)pk[2] | ((uint32_t)pk[3]<<16));
      }
    }
  }
  float* bk = bkt(hdr, b);
  #pragma unroll
  for (int reg=0;reg<4;reg++){
    float s = sacc[reg], qq = qacc[reg];
    for (int o=8;o;o>>=1){ s += __shfl_down(s,o,16); qq += __shfl_down(qq,o,16); }
    if (r==0){ atomicAdd(&bk[H_DS0+wv*16+q*4+reg], s); atomicAdd(&bk[H_DQ0+wv*16+q*4+reg], qq); }
  }
}

// ---------------- deconv1 class helper: all tables compile-time via template<CL> ----------------
template<int CL>
DEV void dec1_cls(const ushort_t* __restrict__ inp, const ushort_t* __restrict__ WPK,
                  const float* biasr, int cotile, int ph, int r, int q, int b,
                  ushort_t* __restrict__ out, float* sacc, float* qacc){
  constexpr int NCOLv[4]={13,12,13,12}, NPOSv[4]={169,156,156,144}, NTv[4]={11,10,10,9},
                NCHv[4]={2,4,4,8}, KBv[4]={0,2048,6144,10240}, KKv[4]={64,128,128,256},
                PIv[4]={0,0,1,1}, PJv[4]={0,1,0,1};
  constexpr int TOFFv[4][4] = {{0,0,0,0},{1,0,0,0},{13,0,0,0},{14,13,1,0}};
  constexpr int NCH = NCHv[CL];
  bf16x8 af[NCH];
  #pragma unroll
  for (int m=0;m<NCH;m++)
    af[m] = *(const bf16x8*)(WPK + OD1 + KBv[CL] + (cotile*16+r)*KKv[CL] + m*32 + q*8);
  for (int t = ph; t < NTv[CL]; t += 2){
    int p = t*16 + r;
    bool ok = p < NPOSv[CL];
    int pc = ok ? p : 0;
    int a_ = pc/NCOLv[CL], c_ = pc - a_*NCOLv[CL];
    int pb = a_*13 + c_;
    f32x4 acc = {0.f,0.f,0.f,0.f};
    #pragma unroll
    for (int m=0;m<NCH;m++){
      int cell = pb + TOFFv[CL][m>>1];
      int chunk = (m&1)*4 + q;
      int slot = chunk ^ ((cell>>1)&7);
      bf16x8 bv = *(const bf16x8*)&inp[cell*64 + slot*8];
      acc = __builtin_amdgcn_mfma_f32_16x16x32_bf16(af[m], bv, acc, 0, 0, 0);
    }
    if (ok){
      int pos = (2*a_+PIv[CL])*25 + (2*c_+PJv[CL]);
      ushort_t pk[4];
      #pragma unroll
      for (int reg=0;reg<4;reg++){
        float y = acc[reg] + biasr[reg];
        pk[reg] = f2bf(y);
        sacc[reg] += y; qacc[reg] += y*y;
      }
      *(uint2*)&out[((size_t)b*625 + pos)*32 + cotile*16 + q*4] =
        make_uint2((uint32_t)pk[0] | ((uint32_t)pk[1]<<16), (uint32_t)pk[2] | ((uint32_t)pk[3]<<16));
    }
  }
}

// ---------------- deconv1 (MFMA): 64->32, k3 s2 p1, 13->25; 2 class-halves per image, grid 1024 ----------------
__global__ __launch_bounds__(256) void k_deconv1m(
    const ushort_t* __restrict__ g0, const ushort_t* __restrict__ WPK, const float* __restrict__ b1g,
    const float* __restrict__ g, const float* __restrict__ be,
    float* __restrict__ hdr, ushort_t* __restrict__ out){
  __shared__ ushort_t inp[169*64];     // [cell 13x13][ci64], chunk-swizzled (full tile)
  __shared__ float ac[128];
  const int blk = blockIdx.x, b = blk>>1, h = blk&1, tid = threadIdx.x;
  coef_lds(hdr, H_DS0, H_DQ0, g, be, ac, 64, 1.f/(512.f*169.f), tid);
  __syncthreads();
  for (int e = tid; e < 169*8; e += 256){
    int cell = e>>3, ch = e&7;
    uint4 raw = *(const uint4*)&g0[((size_t)b*169 + cell)*64 + ch*8];
    uint4 val = stage_chunk(raw, ac, ch*8, 64);
    int slot = ch ^ ((cell>>1)&7);
    *(uint4*)&inp[cell*64 + slot*8] = val;
  }
  __syncthreads();
  const int wv = tid>>6, lane = tid&63, r = lane&15, q = lane>>4;
  const int cotile = wv&1, ph = wv>>1;
  float biasr[4];
  #pragma unroll
  for (int v=0;v<4;v++) biasr[v] = b1g[cotile*16 + q*4 + v];
  float sacc[4]={0,0,0,0}, qacc[4]={0,0,0,0};
  if (h == 0){
    dec1_cls<0>(inp, WPK, biasr, cotile, ph, r, q, b, out, sacc, qacc);
    dec1_cls<1>(inp, WPK, biasr, cotile, ph, r, q, b, out, sacc, qacc);
  } else {
    dec1_cls<2>(inp, WPK, biasr, cotile, ph, r, q, b, out, sacc, qacc);
    dec1_cls<3>(inp, WPK, biasr, cotile, ph, r, q, b, out, sacc, qacc);
  }
  float* bk = bkt(hdr, blk);
  #pragma unroll
  for (int reg=0;reg<4;reg++){
    float s = sacc[reg], qq = qacc[reg];
    for (int o=8;o;o>>=1){ s += __shfl_down(s,o,16); qq += __shfl_down(qq,o,16); }
    if (r==0){ atomicAdd(&bk[H_DS1+cotile*16+q*4+reg], s); atomicAdd(&bk[H_DQ1+cotile*16+q*4+reg], qq); }
  }
}

// ---------------- deconv2 (MFMA): 32->16, k2 s2 p1 op1, 25->49; 2 class-halves per image, grid 1024 ----------------
__global__ __launch_bounds__(256) void k_deconv2m(
    const ushort_t* __restrict__ g1, const ushort_t* __restrict__ WPK, const float* __restrict__ bg,
    const float* __restrict__ g, const float* __restrict__ be,
    float* __restrict__ hdr, ushort_t* __restrict__ out){
  __shared__ ushort_t inp[625*32];     // [cell 25x25][ci32], chunk-swizzled (full tile)
  __shared__ float ac[64];
  const int blk = blockIdx.x, b = blk>>1, h = blk&1, tid = threadIdx.x;
  coef_lds(hdr, H_DS1, H_DQ1, g, be, ac, 32, 1.f/(512.f*625.f), tid);
  __syncthreads();
  for (int e = tid; e < 625*4; e += 256){
    int cell = e>>2, ch = e&3;
    uint4 raw = *(const uint4*)&g1[((size_t)b*625 + cell)*32 + ch*8];
    uint4 val = stage_chunk(raw, ac, ch*8, 32);
    int slot = ch ^ ((cell>>1)&3);
    *(uint4*)&inp[cell*32 + slot*8] = val;
  }
  __syncthreads();
  const int wv = tid>>6, lane = tid&63, r = lane&15, q = lane>>4;
  const int cl = 2*h + (wv>>1);        // this half owns classes 2h, 2h+1; 2 waves per class
  const int ph = wv&1;
  float biasr[4];
  #pragma unroll
  for (int v=0;v<4;v++) biasr[v] = bg[q*4 + v];
  const int NCOL[4]={25,24,25,24}, NPOS[4]={625,600,600,576}, NT[4]={40,38,38,36},
            TOFF[4]={0,1,25,26};
  const int nc = NCOL[cl], npos = NPOS[cl], nt = NT[cl], toff = TOFF[cl];
  bf16x8 af = *(const bf16x8*)(WPK + OD2 + cl*512 + r*32 + q*8);
  float sacc[4]={0,0,0,0}, qacc[4]={0,0,0,0};
  for (int t = ph; t < nt; t += 2){
    int p = t*16 + r;
    bool ok = p < npos;
    int pc = ok ? p : 0;
    int a_ = pc/nc, c_ = pc - a_*nc;
    int cell = a_*25 + c_ + toff;
    int slot = q ^ ((cell>>1)&3);
    f32x4 acc = {0.f,0.f,0.f,0.f};
    bf16x8 bv = *(const bf16x8*)&inp[cell*32 + slot*8];
    acc = __builtin_amdgcn_mfma_f32_16x16x32_bf16(af, bv, acc, 0, 0, 0);
    if (ok){
      ushort_t pk[4];
      #pragma unroll
      for (int reg=0;reg<4;reg++){
        float y = acc[reg] + biasr[reg];
        pk[reg] = f2bf(y);
        sacc[reg] += y; qacc[reg] += y*y;
      }
      *(uint2*)&out[(((size_t)b*4 + cl)*625 + p)*16 + q*4] =
        make_uint2((uint32_t)pk[0] | ((uint32_t)pk[1]<<16), (uint32_t)pk[2] | ((uint32_t)pk[3]<<16));
    }
  }
  float* bk = bkt(hdr, blk);
  #pragma unroll
  for (int reg=0;reg<4;reg++){
    float s = sacc[reg], qq = qacc[reg];
    for (int o=8;o;o>>=1){ s += __shfl_down(s,o,16); qq += __shfl_down(qq,o,16); }
    if (r==0){ atomicAdd(&bk[H_DS2+q*4+reg], s); atomicAdd(&bk[H_DQ2+q*4+reg], qq); }
  }
}

// ---------------- deconv3: input-location-per-thread; G2BF channel-last -> 2x uint4 loads ----------------
__global__ __launch_bounds__(256) void k_deconv3(const ushort_t* __restrict__ g2, const float* __restrict__ w,
                                                 const float* __restrict__ bias,
                                                 const float* __restrict__ g, const float* __restrict__ be,
                                                 float* __restrict__ hdr, float* __restrict__ out){
  __shared__ float ac[32];
  __shared__ float wl[64];
  const int tid = threadIdx.x;
  coef_lds(hdr, H_DS2, H_DQ2, g, be, ac, 16, 1.f/(512.f*2401.f), tid);
  if (tid >= 64 && tid < 128) wl[tid-64] = w[tid-64];
  __syncthreads();
  int idx = blockIdx.x*256 + tid;
  if (idx >= 512*2401) return;
  int b = idx / 2401; int loc = idx - b*2401;
  int ii = loc / 49, jj = loc - ii*49;
  int pi = ii & 1, pj = jj & 1, cl = pi*2 + pj;
  int a = ii >> 1, c = jj >> 1;
  int nc = pj ? 24 : 25;
  const float b0 = bias[0];
  float acc00 = b0, acc01 = b0, acc10 = b0, acc11 = b0;
  const ushort_t* gp = g2 + (((size_t)b*4 + cl)*625 + a*nc + c)*16;
  ushort_t rv[16];
  *(uint4*)&rv[0] = *(const uint4*)(gp);
  *(uint4*)&rv[8] = *(const uint4*)(gp + 8);
  #pragma unroll
  for (int ci=0; ci<16; ci++){
    float raw = bf2f(rv[ci]);
    float h = fmaxf(fmaf(ac[ci], raw, ac[16+ci]), 0.f);
    acc00 = fmaf(h, wl[ci*4+0], acc00);
    acc01 = fmaf(h, wl[ci*4+1], acc01);
    acc10 = fmaf(h, wl[ci*4+2], acc10);
    acc11 = fmaf(h, wl[ci*4+3], acc11);
  }
  float* op = out + (size_t)b*9604 + (2*ii)*98 + 2*jj;
  op[0]   = 1.f/(1.f + __expf(-acc00));
  op[1]   = 1.f/(1.f + __expf(-acc01));
  op[98]  = 1.f/(1.f + __expf(-acc10));
  op[99]  = 1.f/(1.f + __expf(-acc11));
}

// ======================================================================
extern "C" void kernel_launch(void* const* d_in, const int* in_sizes, int n_in,
                              void* d_out, int out_size, void* d_ws, size_t ws_size,
                              hipStream_t stream){
  (void)in_sizes; (void)n_in; (void)out_size; (void)ws_size;
  const float* x     = (const float*)d_in[0];
  const float* c1w   = (const float*)d_in[1];
  const float* c1b   = (const float*)d_in[2];
  const float* bn1g  = (const float*)d_in[3];
  const float* bn1b  = (const float*)d_in[4];
  const float* c2w   = (const float*)d_in[5];
  const float* c2b   = (const float*)d_in[6];
  const float* bn2g  = (const float*)d_in[7];
  const float* bn2b  = (const float*)d_in[8];
  const float* c3w   = (const float*)d_in[9];
  const float* c3b   = (const float*)d_in[10];
  const float* bn3g  = (const float*)d_in[11];
  const float* bn3b  = (const float*)d_in[12];
  const float* c4w   = (const float*)d_in[13];
  const float* c4b   = (const float*)d_in[14];
  const float* bn4g  = (const float*)d_in[15];
  const float* bn4b  = (const float*)d_in[16];
  const float* mem   = (const float*)d_in[17];
  const float* d0w   = (const float*)d_in[18];
  const float* d0b   = (const float*)d_in[19];
  const float* dbn0g = (const float*)d_in[20];
  const float* dbn0b = (const float*)d_in[21];
  const float* d1w   = (const float*)d_in[22];
  const float* d1b   = (const float*)d_in[23];
  const float* dbn1g = (const float*)d_in[24];
  const float* dbn1b = (const float*)d_in[25];
  const float* d2w   = (const float*)d_in[26];
  const float* d2b   = (const float*)d_in[27];
  const float* dbn2g = (const float*)d_in[28];
  const float* dbn2b = (const float*)d_in[29];
  const float* d3w   = (const float*)d_in[30];
  const float* d3b   = (const float*)d_in[31];

  float* hdr  = (float*)d_ws;
  float* H2f  = hdr + HDR_FLOATS;        // slot: H2CL bf16 (10.24M ushort) / later G1CL
  float* H3f  = H2f + 10240000;          // slot: H3CL bf16 (5.54M ushort) / later G0CL
  float* ZRAW = H3f + 5537792;           // 512*2304 fp32
  float* WSLOT= ZRAW + 1179648;          // 73728 floats (holds WPK bf16)
  float* G2   = WSLOT + 73728;           // 19.67M floats scratch region
  ushort_t* MEMBF = (ushort_t*)(G2 + 19668992); // 2000*2304
  ushort_t* MEMT  = MEMBF + 4608000;            // 2304*2016
  ushort_t* ZBF   = MEMT + 4644864;             // 512*2304 (unused this rev)
  ushort_t* WBF   = ZBF + 1179648;              // 512*2016
  ushort_t* WPK   = (ushort_t*)WSLOT;
  float* SIMP = G2;                      // NSPLA * 512*2000 = 8.19M floats
  float* ZHP  = G2 + (size_t)NSPLA*SIMSTRIDE;   // NSPLB * 512*2304 = 8.26M floats
  ushort_t* G2BF = (ushort_t*)G2;        // 512*4*625*16 bf16 (SIMP/ZHP dead by then)
  ushort_t* H2CL = (ushort_t*)H2f;
  ushort_t* H3CL = (ushort_t*)H3f;
  ushort_t* G0CL = (ushort_t*)H3f;       // reuse (H3CL dead after conv4m)
  ushort_t* G1CL = (ushort_t*)H2f;       // reuse (H2CL dead after conv3m)
  float* OUT = (float*)d_out;

  hipMemsetAsync(hdr, 0, HDR_FLOATS*sizeof(float), stream);
  k_prep     <<<PREP_TOT, 256, 0, stream>>>(mem, MEMBF, MEMT, hdr,
                                            c2w, c3w, c4w, d0w, d1w, d2w, WPK, x);
  k_conv2m   <<<1024, 256, 0, stream>>>(x, WPK, c2b, c1w, c1b, bn1g, bn1b, hdr, H2CL);
  k_conv3m   <<<1024, 256, 0, stream>>>(H2CL, WPK, c3b, bn2g, bn2b, hdr, H3CL);
  k_conv4m   <<<1024, 256, 0, stream>>>(H3CL, WPK, c4b, bn3g, bn3b, hdr, ZRAW);
  k_gemmA    <<<512, 256, 0, stream>>>(ZRAW, MEMBF, SIMP, bn4g, bn4b, hdr);
  k_softmax  <<<512, 256, 0, stream>>>(SIMP, hdr, WBF);
  k_gemmB    <<<504, 256, 0, stream>>>(WBF, MEMT, ZHP, 18, 2304, 2016, 63, 72, 9, ZHSTRIDE);
  k_deconv0m <<<512, 256, 0, stream>>>(ZHP, WPK, d0b, hdr, G0CL);
  k_deconv1m <<<1024, 256, 0, stream>>>(G0CL, WPK, d1b, dbn0g, dbn0b, hdr, G1CL);
  k_deconv2m <<<1024, 256, 0, stream>>>(G1CL, WPK, d2b, dbn1g, dbn1b, hdr, G2BF);
  k_deconv3  <<<4802, 256, 0, stream>>>(G2BF, d3w, d3b, dbn2g, dbn2b, hdr, OUT);
}

// Round 11
// 319.849 us; speedup vs baseline: 2.3409x; 1.0359x over previous
//
#include <hip/hip_runtime.h>
#include <stdint.h>

// R18 = R15 (best verified: 320.6us). Final configuration.
// Session summary: 355.4 (R9) -> 320.6 via memory-access fixes:
//  - deconv0: coalesced f32x4 partial-sum + XOR LDS swizzle (R12)
//  - prep mem-tiles 32x128 f32x4/uint2; G2BF channel-last for deconv3 (R13)
//  - balanced split-K: gemmA 8 (512 blk), gemmB 7 (504 blk) (R15)
// TLP/structural levers (dispatch fusion, grid overlap, spatial splits) all
// measured neutral-to-negative; BN-training's 12 serial barriers + small
// per-layer shapes are the structural plateau at HIP source level.

typedef unsigned short ushort_t;
typedef __bf16 bf16x8 __attribute__((ext_vector_type(8)));
typedef float f32x4 __attribute__((ext_vector_type(4)));

#define DEV static __device__ __forceinline__

DEV ushort_t f2bf(float f){
  union { float f; uint32_t u; } v; v.f = f;
  return (ushort_t)((v.u + 0x7FFFu + ((v.u >> 16) & 1u)) >> 16);
}
DEV float bf2f(ushort_t u){
  union { uint32_t u; float f; } v; v.u = ((uint32_t)u) << 16;
  return v.f;
}

// affine+relu two packed bf16 (raw) -> packed bf16
DEV uint32_t affine2(uint32_t rw, const float* ac, int ci, int nch){
  float lo = bf2f((ushort_t)(rw & 0xffffu));
  float hi = bf2f((ushort_t)(rw >> 16));
  lo = fmaxf(fmaf(ac[ci],   lo, ac[nch+ci]),   0.f);
  hi = fmaxf(fmaf(ac[ci+1], hi, ac[nch+ci+1]), 0.f);
  return (uint32_t)f2bf(lo) | ((uint32_t)f2bf(hi) << 16);
}
DEV uint4 stage_chunk(uint4 raw, const float* ac, int ci0, int nch){
  uint4 o;
  o.x = affine2(raw.x, ac, ci0+0, nch);
  o.y = affine2(raw.y, ac, ci0+2, nch);
  o.z = affine2(raw.z, ac, ci0+4, nch);
  o.w = affine2(raw.w, ac, ci0+6, nch);
  return o;
}

// ---------------- header (stats/coeff) offsets in floats ----------------
#define H_XS   0
#define H_S2   64
#define H_Q2   96
#define H_S3   192
#define H_Q3   256
#define H_S4   448
#define H_Q4   512
#define H_DS0  704
#define H_DQ0  768
#define H_DS1  960
#define H_DQ1  992
#define H_DS2  1088
#define H_DQ2  1104
#define H_ZN   1152   // [512]  sum of z^2 per row (softmax takes sqrtf)
#define H_MN   1664   // [2000] sum of mem^2 per row (softmax takes sqrtf)
#define H_BUK  4096   // 16 bucket banks of 1280 floats each
#define NBUK   16
#define BSTRIDE 1280
#define HDR_FLOATS (H_BUK + NBUK*BSTRIDE)

// packed-weight (bf16) offsets in WPK
#define OW2 0        // [32][160]  k=tap*16+ci, taps 0..9 (tap9 = zero pad)
#define OW3 5120     // [64][288]  k=tap*32+ci
#define OW4 23552    // [64][576]  k=tap*64+ci
#define OD0 60416    // 4 classes [64][K], K={256,128,128,64}
#define OD1 97280    // 4 classes [32][K], K={64,128,128,256}
#define OD2 115712   // 4 classes [16][32]
#define NWPK 117760

#define SIMSTRIDE 1024000   // 512*2000
#define ZHSTRIDE  1179648   // 512*2304
#define NSPLA 8             // split-K partials for GEMM1 (512 blocks)
#define NSPLB 7             // split-K partials for GEMM2 (504 blocks)

// k_prep block ranges: xstats, wprep, mem tiles (32m x 128f)
#define PREP_XS 256
#define PREP_W2 (PREP_XS + 460)      // 460*256 >= NWPK
#define PREP_TOT (PREP_W2 + 63*18)   // 63 mtiles * 18 ftiles = 1134

DEV float* bkt(float* hdr, int blk){ return hdr + H_BUK + (size_t)(blk & (NBUK-1))*BSTRIDE; }

DEV void coef_lds(const float* __restrict__ hdr, int offS, int offQ,
                  const float* __restrict__ g, const float* __restrict__ be,
                  float* ac, int nch, float invN, int tid){
  if (tid < nch){
    float s = 0.f, q = 0.f;
    #pragma unroll
    for (int k=0;k<NBUK;k++){
      s += hdr[H_BUK + k*BSTRIDE + offS + tid];
      q += hdr[H_BUK + k*BSTRIDE + offQ + tid];
    }
    float m = s*invN;
    float v = q*invN - m*m;
    float a = g[tid]*rsqrtf(v + 1e-5f);
    ac[tid] = a;
    ac[nch+tid] = be[tid] - m*a;
  }
}

// ---------------- fused prep: xstats, wprep, mem tiles (bf16 + transpose + norms) ----------------
__global__ __launch_bounds__(256) void k_prep(
    const float* __restrict__ mem, ushort_t* __restrict__ mbf, ushort_t* __restrict__ mt,
    float* __restrict__ hdr,
    const float* __restrict__ c2w, const float* __restrict__ c3w, const float* __restrict__ c4w,
    const float* __restrict__ d0w, const float* __restrict__ d1w, const float* __restrict__ d2w,
    ushort_t* __restrict__ WPK, const float* __restrict__ x){
  __shared__ ushort_t smu[32*132];    // mem branch: bf16 tile [32m][128f +4 pad]; xstats: 8 floats
  const int blk = blockIdx.x, tid = threadIdx.x;
  if (blk < PREP_XS){
    // xstats: strided-sampled input stats for bn1 fold (256 blocks, grid-stride)
    float* sm = (float*)smu;
    float s = 0.f, q = 0.f;
    const int total = 512*49*49;
    for (int idx = blk*256 + tid; idx < total; idx += 256*256){
      int b = idx / 2401;
      int r = idx - b*2401;
      int i = r / 49, j = r - i*49;
      float v = 0.f;
      if (i > 0 && j > 0) v = x[(size_t)b*9216 + (2*i-1)*96 + (2*j-1)];
      s += v; q += v*v;
    }
    for (int o=32;o;o>>=1){ s += __shfl_down(s,o,64); q += __shfl_down(q,o,64); }
    int w = tid>>6;
    if ((tid&63)==0){ sm[w*2]=s; sm[w*2+1]=q; }
    __syncthreads();
    if (tid==0){
      float* bk = bkt(hdr, blk);
      atomicAdd(&bk[H_XS+0], sm[0]+sm[2]+sm[4]+sm[6]);
      atomicAdd(&bk[H_XS+1], sm[1]+sm[3]+sm[5]+sm[7]);
    }
  } else if (blk < PREP_W2){
    // weight pack
    int i = (blk - PREP_XS)*256 + tid;
    if (i >= NWPK) return;
    float val = 0.f;
    if (i < OW3){                       // conv2 [32][160]
      int co = i/160, k = i - co*160, tap = k>>4, ci = k&15;
      if (tap < 9) val = c2w[(co*16+ci)*9+tap];
    } else if (i < OW4){                // conv3 [64][288]
      int r = i - OW3; int co = r/288, k = r - co*288, tap = k>>5, ci = k&31;
      val = c3w[(co*32+ci)*9+tap];
    } else if (i < OD0){                // conv4 [64][576]
      int r = i - OW4; int co = r/576, k = r - co*576, tap = k>>6, ci = k&63;
      val = c4w[(co*64+ci)*9+tap];
    } else if (i < OD1){                // deconv0 classes
      int r = i - OD0;
      const int base[4]={0,16384,24576,32768}, K[4]={256,128,128,64};
      const int T0[4][4] = {{0,2,6,8},{1,7,0,0},{3,5,0,0},{4,0,0,0}};
      int cl = (r<16384)?0:(r<24576)?1:(r<32768)?2:3;
      int rr = r - base[cl]; int co = rr/K[cl], k = rr - co*K[cl], t = k>>6, ci = k&63;
      val = d0w[(ci*64+co)*9 + T0[cl][t]];
    } else if (i < OD2){                // deconv1 classes
      int r = i - OD1;
      const int base[4]={0,2048,6144,10240}, K[4]={64,128,128,256};
      const int T1[4][4] = {{4,0,0,0},{3,5,0,0},{1,7,0,0},{0,2,6,8}};
      int cl = (r<2048)?0:(r<6144)?1:(r<10240)?2:3;
      int rr = r - base[cl]; int co = rr/K[cl], k = rr - co*K[cl], t = k>>6, ci = k&63;
      val = d1w[(ci*32+co)*9 + T1[cl][t]];
    } else {                            // deconv2 classes [4][16][32]
      int r = i - OD2;
      int cl = r>>9, s = r&511, co = s>>5, ci = s&31;
      const int pis[4]={0,0,1,1}, pjs[4]={0,1,0,1};
      val = d2w[((ci*16+co)*2 + (1-pis[cl]))*2 + (1-pjs[cl])];
    }
    WPK[i] = f2bf(val);
  } else {
    // 32m x 128f tile of memory: f32x4 read once, write MEMBF (uint2) + MEMT + norm^2 partials
    const int mb = blk - PREP_W2;
    const int ft = mb % 18, mtile = mb / 18;
    const int tx = tid & 31, ty = tid >> 5;
    #pragma unroll
    for (int r0=0;r0<4;r0++){
      int m = mtile*32 + r0*8 + ty;
      int f = ft*128 + tx*4;
      f32x4 v = {0.f,0.f,0.f,0.f};
      if (m < 2000) v = *(const f32x4*)&mem[(size_t)m*2304 + f];
      ushort_t h0=f2bf(v[0]), h1=f2bf(v[1]), h2=f2bf(v[2]), h3=f2bf(v[3]);
      uint2 pk = make_uint2((uint32_t)h0 | ((uint32_t)h1<<16), (uint32_t)h2 | ((uint32_t)h3<<16));
      *(uint2*)&smu[(r0*8+ty)*132 + tx*4] = pk;
      if (m < 2000) *(uint2*)&mbf[(size_t)m*2304 + f] = pk;
      float p = v[0]*v[0] + v[1]*v[1] + v[2]*v[2] + v[3]*v[3];
      for (int o=16;o;o>>=1) p += __shfl_down(p, o, 32);
      if (tx==0 && m<2000) atomicAdd(&hdr[H_MN+m], p);
    }
    __syncthreads();
    #pragma unroll
    for (int ff=0; ff<16; ff++){
      int fl = ff*8 + ty;
      mt[(size_t)(ft*128 + fl)*2016 + mtile*32 + tx] = smu[tx*132 + fl];
    }
  }
}

// ---------------- conv2 (MFMA): 16->32, 3x3 s2 p1; writes H2CL [b][625][32] raw bf16 ----------------
__global__ __launch_bounds__(256) void k_conv2m(
    const float* __restrict__ x, const ushort_t* __restrict__ WPK, const float* __restrict__ b2g,
    const float* __restrict__ c1w, const float* __restrict__ c1b,
    const float* __restrict__ bn1g, const float* __restrict__ bn1b,
    float* __restrict__ hdr, ushort_t* __restrict__ out){
  __shared__ ushort_t inp[27*51*16];    // [row][col][ci16], halo'd 51-grid rows [2*ro..2*ro+26]
  __shared__ float ac[32];
  const int blk = blockIdx.x, b = blk>>1, h = blk&1, tid = threadIdx.x;
  const int ro = h*13, nr = h?12:13, npos = nr*25, ntiles = (npos+15)>>4;
  if (tid < 16){
    float sx=0.f, qx=0.f;
    #pragma unroll
    for (int k=0;k<NBUK;k++){ sx += hdr[H_BUK+k*BSTRIDE+H_XS]; qx += hdr[H_BUK+k*BSTRIDE+H_XS+1]; }
    const float N = 512.f*49.f*49.f;
    float mx = sx/N, vx = qx/N - mx*mx;
    float mean = c1w[tid]*mx + c1b[tid];
    float a = bn1g[tid]*rsqrtf(c1w[tid]*c1w[tid]*vx + 1e-5f);
    ac[tid] = a*c1w[tid];
    ac[16+tid] = a*(c1b[tid]-mean) + bn1b[tid];
  }
  __syncthreads();
  for (int e = tid; e < 27*51; e += 256){
    int lr = e/51, gc = e - lr*51;
    int grg = 2*ro + lr;
    bool inside = (grg>=1 && grg<=49 && gc>=1 && gc<=49);
    float v = 0.f;
    if (grg>=2 && grg<=49 && gc>=2 && gc<=49) v = x[(size_t)b*9216 + (2*grg-3)*96 + (2*gc-3)];
    ushort_t hv[16];
    if (inside){
      #pragma unroll
      for (int c=0;c<16;c++) hv[c] = f2bf(fmaxf(fmaf(ac[c], v, ac[16+c]), 0.f));
    } else {
      #pragma unroll
      for (int c=0;c<16;c++) hv[c] = 0;
    }
    uint32_t w0[8];
    #pragma unroll
    for (int c=0;c<8;c++) w0[c] = (uint32_t)hv[2*c] | ((uint32_t)hv[2*c+1]<<16);
    uint4* dst = (uint4*)&inp[e*16];
    dst[0] = make_uint4(w0[0],w0[1],w0[2],w0[3]);
    dst[1] = make_uint4(w0[4],w0[5],w0[6],w0[7]);
  }
  __syncthreads();
  const int wv = tid>>6, lane = tid&63, r = lane&15, q = lane>>4;
  const int cotile = wv&1;
  bf16x8 af[5];
  #pragma unroll
  for (int c=0;c<5;c++) af[c] = *(const bf16x8*)(WPK + OW2 + (cotile*16+r)*160 + c*32 + q*8);
  float biasr[4];
  #pragma unroll
  for (int v=0;v<4;v++) biasr[v] = b2g[cotile*16 + q*4 + v];
  const int TOFF[10] = {0,1,2,51,52,53,102,103,104,0};
  const int qhi = q>>1, ci0 = (q&1)*8;
  float sacc[4]={0,0,0,0}, qacc[4]={0,0,0,0};
  for (int t = wv>>1; t < ntiles; t += 2){
    int p = t*16 + r;
    bool ok = p < npos;
    int pc = ok ? p : 0;
    int a_ = pc/25, c_ = pc - a_*25;
    int pb = (2*a_)*51 + 2*c_;
    f32x4 acc = {0.f,0.f,0.f,0.f};
    #pragma unroll
    for (int c=0;c<5;c++){
      int toff = qhi ? TOFF[2*c+1] : TOFF[2*c];
      bf16x8 bv = *(const bf16x8*)&inp[(pb + toff)*16 + ci0];
      acc = __builtin_amdgcn_mfma_f32_16x16x32_bf16(af[c], bv, acc, 0, 0, 0);
    }
    if (ok){
      int pg = (ro + a_)*25 + c_;
      ushort_t pk[4];
      #pragma unroll
      for (int reg=0;reg<4;reg++){
        float y = acc[reg] + biasr[reg];
        pk[reg] = f2bf(y);
        sacc[reg] += y; qacc[reg] += y*y;
      }
      *(uint2*)&out[((size_t)b*625 + pg)*32 + cotile*16 + q*4] =
        make_uint2((uint32_t)pk[0] | ((uint32_t)pk[1]<<16), (uint32_t)pk[2] | ((uint32_t)pk[3]<<16));
    }
  }
  float* bk = bkt(hdr, blk);
  #pragma unroll
  for (int reg=0;reg<4;reg++){
    float s = sacc[reg], qq = qacc[reg];
    for (int o=8;o;o>>=1){ s += __shfl_down(s,o,16); qq += __shfl_down(qq,o,16); }
    if (r==0){ atomicAdd(&bk[H_S2+cotile*16+q*4+reg], s); atomicAdd(&bk[H_Q2+cotile*16+q*4+reg], qq); }
  }
}

// ---------------- conv3 (MFMA): 32->64, 3x3 s2 p1, 25->13; 2 spatial halves per image ----------------
__global__ __launch_bounds__(256) void k_conv3m(
    const ushort_t* __restrict__ h2, const ushort_t* __restrict__ WPK, const float* __restrict__ b3g,
    const float* __restrict__ g, const float* __restrict__ be,
    float* __restrict__ hdr, ushort_t* __restrict__ out){
  __shared__ ushort_t inp[15*27*32];   // [lr][lc][ci32], chunk-swizzled
  __shared__ float ac[64];
  const int blk = blockIdx.x, b = blk>>1, h = blk&1, tid = threadIdx.x;
  const int a0 = h*7, na = h?6:7, npos = na*13, ntiles = (npos+15)>>4, nrows = 2*na+1;
  coef_lds(hdr, H_S2, H_Q2, g, be, ac, 32, 1.f/(512.f*625.f), tid);
  __syncthreads();
  for (int e = tid; e < nrows*27*4; e += 256){
    int cell = e>>2, ch = e&3;
    int lr = cell/27, lc = cell - lr*27;
    int ii = 2*a0 - 1 + lr, j = lc - 1;
    uint4 val = make_uint4(0,0,0,0);
    if ((unsigned)ii < 25u && (unsigned)j < 25u){
      uint4 raw = *(const uint4*)&h2[((size_t)b*625 + ii*25 + j)*32 + ch*8];
      val = stage_chunk(raw, ac, ch*8, 32);
    }
    int slot = ch ^ ((cell>>1)&3);
    *(uint4*)&inp[cell*32 + slot*8] = val;
  }
  __syncthreads();
  const int wv = tid>>6, lane = tid&63, r = lane&15, q = lane>>4;
  bf16x8 af[9];
  #pragma unroll
  for (int c=0;c<9;c++) af[c] = *(const bf16x8*)(WPK + OW3 + (wv*16+r)*288 + c*32 + q*8);
  float biasr[4];
  #pragma unroll
  for (int v=0;v<4;v++) biasr[v] = b3g[wv*16 + q*4 + v];
  const int TOFF[9] = {0,1,2,27,28,29,54,55,56};
  float sacc[4]={0,0,0,0}, qacc[4]={0,0,0,0};
  for (int t = 0; t < ntiles; t++){
    int p = t*16 + r;
    bool ok = p < npos;
    int pc = ok ? p : 0;
    int a_ = pc/13, c_ = pc - a_*13;
    int pb = (2*a_)*27 + 2*c_;
    f32x4 acc = {0.f,0.f,0.f,0.f};
    #pragma unroll
    for (int c=0;c<9;c++){
      int cell = pb + TOFF[c];
      int slot = q ^ ((cell>>1)&3);
      bf16x8 bv = *(const bf16x8*)&inp[cell*32 + slot*8];
      acc = __builtin_amdgcn_mfma_f32_16x16x32_bf16(af[c], bv, acc, 0, 0, 0);
    }
    if (ok){
      int pos = (a0 + a_)*13 + c_;
      ushort_t pk[4];
      #pragma unroll
      for (int reg=0;reg<4;reg++){
        float y = acc[reg] + biasr[reg];
        pk[reg] = f2bf(y);
        sacc[reg] += y; qacc[reg] += y*y;
      }
      *(uint2*)&out[((size_t)b*169 + pos)*64 + wv*16 + q*4] =
        make_uint2((uint32_t)pk[0] | ((uint32_t)pk[1]<<16), (uint32_t)pk[2] | ((uint32_t)pk[3]<<16));
    }
  }
  float* bk = bkt(hdr, blk);
  #pragma unroll
  for (int reg=0;reg<4;reg++){
    float s = sacc[reg], qq = qacc[reg];
    for (int o=8;o;o>>=1){ s += __shfl_down(s,o,16); qq += __shfl_down(qq,o,16); }
    if (r==0){ atomicAdd(&bk[H_S3+wv*16+q*4+reg], s); atomicAdd(&bk[H_Q3+wv*16+q*4+reg], qq); }
  }
}

// ---------------- conv4 (MFMA): 64->64, 3x3 s2 p0, 13->6; in: H3CL raw bf16 ----------------
__global__ __launch_bounds__(256) void k_conv4m(
    const ushort_t* __restrict__ h3, const ushort_t* __restrict__ WPK, const float* __restrict__ b4g,
    const float* __restrict__ g, const float* __restrict__ be,
    float* __restrict__ hdr, float* __restrict__ out){
  __shared__ ushort_t inp[169*64];     // [cell][ci64], chunk-swizzled
  __shared__ float ac[128];
  const int b = blockIdx.x, tid = threadIdx.x;
  coef_lds(hdr, H_S3, H_Q3, g, be, ac, 64, 1.f/(512.f*169.f), tid);
  __syncthreads();
  for (int e = tid; e < 169*8; e += 256){
    int cell = e>>3, ch = e&7;
    uint4 raw = *(const uint4*)&h3[((size_t)b*169 + cell)*64 + ch*8];
    uint4 val = stage_chunk(raw, ac, ch*8, 64);
    int slot = ch ^ ((cell>>1)&7);
    *(uint4*)&inp[cell*64 + slot*8] = val;
  }
  __syncthreads();
  const int wv = tid>>6, lane = tid&63, r = lane&15, q = lane>>4;
  bf16x8 af[18];
  #pragma unroll
  for (int c=0;c<18;c++) af[c] = *(const bf16x8*)(WPK + OW4 + (wv*16+r)*576 + c*32 + q*8);
  float biasr[4];
  #pragma unroll
  for (int v=0;v<4;v++) biasr[v] = b4g[wv*16 + q*4 + v];
  const int TOFF[9] = {0,1,2,13,14,15,26,27,28};
  float sacc[4]={0,0,0,0}, qacc[4]={0,0,0,0};
  for (int t = 0; t < 3; t++){
    int p = t*16 + r;
    bool ok = p < 36;
    int pc = ok ? p : 0;
    int a_ = pc/6, c_ = pc - a_*6;
    int pb = (2*a_)*13 + 2*c_;
    f32x4 acc = {0.f,0.f,0.f,0.f};
    #pragma unroll
    for (int c=0;c<18;c++){
      int cell = pb + TOFF[c>>1];
      int chunk = (c&1)*4 + q;
      int slot = chunk ^ ((cell>>1)&7);
      bf16x8 bv = *(const bf16x8*)&inp[cell*64 + slot*8];
      acc = __builtin_amdgcn_mfma_f32_16x16x32_bf16(af[c], bv, acc, 0, 0, 0);
    }
    if (ok){
      #pragma unroll
      for (int reg=0;reg<4;reg++){
        float y = acc[reg] + biasr[reg];
        out[((size_t)b*64 + wv*16 + q*4 + reg)*36 + p] = y;
        sacc[reg] += y; qacc[reg] += y*y;
      }
    }
  }
  float* bk = bkt(hdr, b);
  #pragma unroll
  for (int reg=0;reg<4;reg++){
    float s = sacc[reg], qq = qacc[reg];
    for (int o=8;o;o>>=1){ s += __shfl_down(s,o,16); qq += __shfl_down(qq,o,16); }
    if (r==0){ atomicAdd(&bk[H_S4+wv*16+q*4+reg], s); atomicAdd(&bk[H_Q4+wv*16+q*4+reg], qq); }
  }
}

// ---------------- GEMM1 with fused z = relu(bn4(ZRAW)) on A-stage + z-norm^2 atomics ----------------
// A: ZRAW fp32 [512][2304] (k = c*36+p), B: MEMBF bf16 [2000][2304], D: SIMP NSPLA partials
__global__ __launch_bounds__(256) void k_gemmA(
    const float* __restrict__ ZR, const ushort_t* __restrict__ Bm, float* __restrict__ D,
    const float* __restrict__ g, const float* __restrict__ be, float* __restrict__ hdr){
  __shared__ __align__(16) ushort_t lB[128*40];
  __shared__ __align__(16) ushort_t lA[128*40];
  __shared__ float ac[128];
  const int blk = blockIdx.x;
  const int s = blk >> 6, t = blk & 63;          // 8 splits x 64 tiles = 512 blocks
  const int bi = t >> 4, bj = t & 15;
  const int m0 = bi*128, n0 = bj*128;
  const int k0 = s*9, k1 = k0 + 9;               // 72 k-steps / 8
  const int tid = threadIdx.x;
  coef_lds(hdr, H_S4, H_Q4, g, be, ac, 64, 1.f/(512.f*36.f), tid);
  const int lane = tid & 63, wv = tid >> 6;
  const int r = lane & 15, q = lane >> 4;
  const int wr = wv >> 1, wc = wv & 1;
  const bool bj0 = (bj == 0);
  float* Ds = D + (size_t)s*SIMSTRIDE;
  const int srow = tid >> 1, skq = (tid & 1) * 16;
  const bool bok = (n0 + srow) < 2000;
  const ushort_t* pb = Bm + (size_t)(n0 + srow)*2304 + skq;
  const float*    pa = ZR + (size_t)(m0 + srow)*2304 + skq;
  uint4* wB = (uint4*)&lB[srow*40 + skq];
  uint4* wA = (uint4*)&lA[srow*40 + skq];
  const uint4 zz = make_uint4(0,0,0,0);
  uint4 rb0 = bok ? *(const uint4*)(pb + (size_t)k0*32)     : zz;
  uint4 rb1 = bok ? *(const uint4*)(pb + (size_t)k0*32 + 8) : zz;
  f32x4 raA[4];
  #pragma unroll
  for (int i=0;i<4;i++) raA[i] = *(const f32x4*)(pa + (size_t)k0*32 + i*4);
  f32x4 acc[4][4];
  #pragma unroll
  for (int i=0;i<4;i++)
    #pragma unroll
    for (int j=0;j<4;j++) acc[i][j] = (f32x4){0.f,0.f,0.f,0.f};
  float zsq = 0.f;
  __syncthreads();   // ac ready
  for (int k=k0; k<k1; k++){
    if (k > k0) __syncthreads();
    wB[0] = rb0; wB[1] = rb1;
    {
      const int kb = k*32 + skq;
      uint32_t pw[8];
      #pragma unroll
      for (int jj=0;jj<8;jj++){
        float v0 = raA[jj>>1][(jj&1)*2+0];
        float v1 = raA[jj>>1][(jj&1)*2+1];
        int c0 = (kb + 2*jj) / 36;
        int c1 = (kb + 2*jj + 1) / 36;
        float h0 = fmaxf(fmaf(ac[c0], v0, ac[64+c0]), 0.f);
        float h1 = fmaxf(fmaf(ac[c1], v1, ac[64+c1]), 0.f);
        if (bj0) zsq += h0*h0 + h1*h1;
        pw[jj] = (uint32_t)f2bf(h0) | ((uint32_t)f2bf(h1) << 16);
      }
      wA[0] = make_uint4(pw[0],pw[1],pw[2],pw[3]);
      wA[1] = make_uint4(pw[4],pw[5],pw[6],pw[7]);
    }
    if (k+1 < k1){
      const ushort_t* nb = pb + (size_t)(k+1)*32;
      rb0 = bok ? *(const uint4*)(nb)     : zz;
      rb1 = bok ? *(const uint4*)(nb + 8) : zz;
      const float* na = pa + (size_t)(k+1)*32;
      #pragma unroll
      for (int i=0;i<4;i++) raA[i] = *(const f32x4*)(na + i*4);
    }
    __syncthreads();
    bf16x8 aF[4], bF[4];
    #pragma unroll
    for (int mt=0;mt<4;mt++) aF[mt] = *(const bf16x8*)&lA[(wr*64+mt*16+r)*40 + q*8];
    #pragma unroll
    for (int nt=0;nt<4;nt++) bF[nt] = *(const bf16x8*)&lB[(wc*64+nt*16+r)*40 + q*8];
    #pragma unroll
    for (int mt=0;mt<4;mt++)
      #pragma unroll
      for (int nt=0;nt<4;nt++)
        acc[mt][nt] = __builtin_amdgcn_mfma_f32_16x16x32_bf16(aF[mt], bF[nt], acc[mt][nt], 0, 0, 0);
  }
  if (bj0){
    zsq += __shfl_down(zsq, 1, 64);
    if ((tid & 1) == 0) atomicAdd(&hdr[H_ZN + m0 + srow], zsq);
  }
  #pragma unroll
  for (int mt=0;mt<4;mt++){
    int row = m0 + wr*64 + mt*16 + q*4;
    #pragma unroll
    for (int nt=0;nt<4;nt++){
      int col = n0 + wc*64 + nt*16 + r;
      if (col < 2000){
        #pragma unroll
        for (int reg=0;reg<4;reg++)
          Ds[(size_t)(row+reg)*2000 + col] = acc[mt][nt][reg];
      }
    }
  }
}

// ---------------- blocked GEMM, split-K (GEMM2) ----------------
__global__ __launch_bounds__(256) void k_gemmB(const ushort_t* __restrict__ A, const ushort_t* __restrict__ Bm,
                                               float* __restrict__ D, int Nb, int N, int Kp, int kch,
                                               int tiles, int ksp, size_t dstride){
  __shared__ __align__(16) ushort_t lB[128*40];
  const int blk = blockIdx.x;
  const int s = blk / tiles, t = blk - s*tiles;
  const int bi = t / Nb, bj = t - bi*Nb;
  const int m0 = bi*128, n0 = bj*128;
  const int k0 = s*ksp, k1 = min(kch, k0 + ksp);
  const int tid = threadIdx.x;
  const int lane = tid & 63, wv = tid >> 6;
  const int r = lane & 15, q = lane >> 4;
  const int wr = wv >> 1, wc = wv & 1;
  float* Ds = D + (size_t)s*dstride;
  const int srow = tid >> 1, skq = (tid & 1) * 16;
  const bool bok = (n0 + srow) < N;
  const ushort_t* pb = Bm + (size_t)(n0 + srow)*Kp + skq;
  uint4* wB = (uint4*)&lB[srow*40 + skq];
  const uint4 zz = make_uint4(0,0,0,0);
  uint4 rb0 = bok ? *(const uint4*)(pb + k0*32)     : zz;
  uint4 rb1 = bok ? *(const uint4*)(pb + k0*32 + 8) : zz;
  const ushort_t* pa = A + (size_t)(m0 + wr*64 + r)*Kp + q*8;
  bf16x8 aN[4];
  #pragma unroll
  for (int mt=0;mt<4;mt++) aN[mt] = *(const bf16x8*)(pa + k0*32 + (size_t)(mt*16)*Kp);
  f32x4 acc[4][4];
  #pragma unroll
  for (int i=0;i<4;i++)
    #pragma unroll
    for (int j=0;j<4;j++) acc[i][j] = (f32x4){0.f,0.f,0.f,0.f};
  for (int k=k0; k<k1; k++){
    if (k > k0) __syncthreads();
    wB[0] = rb0; wB[1] = rb1;
    bf16x8 aF[4];
    #pragma unroll
    for (int mt=0;mt<4;mt++) aF[mt] = aN[mt];
    if (k+1 < k1){
      const ushort_t* nb = pb + (k+1)*32;
      rb0 = bok ? *(const uint4*)(nb)     : zz;
      rb1 = bok ? *(const uint4*)(nb + 8) : zz;
      const ushort_t* na = pa + (k+1)*32;
      #pragma unroll
      for (int mt=0;mt<4;mt++) aN[mt] = *(const bf16x8*)(na + (size_t)(mt*16)*Kp);
    }
    __syncthreads();
    bf16x8 bF[4];
    #pragma unroll
    for (int nt=0;nt<4;nt++) bF[nt] = *(const bf16x8*)&lB[(wc*64+nt*16+r)*40 + q*8];
    #pragma unroll
    for (int mt=0;mt<4;mt++)
      #pragma unroll
      for (int nt=0;nt<4;nt++)
        acc[mt][nt] = __builtin_amdgcn_mfma_f32_16x16x32_bf16(aF[mt], bF[nt], acc[mt][nt], 0, 0, 0);
  }
  #pragma unroll
  for (int mt=0;mt<4;mt++){
    int row = m0 + wr*64 + mt*16 + q*4;
    #pragma unroll
    for (int nt=0;nt<4;nt++){
      int col = n0 + wc*64 + nt*16 + r;
      if (col < N){
        #pragma unroll
        for (int reg=0;reg<4;reg++)
          Ds[(size_t)(row+reg)*N + col] = acc[mt][nt][reg];
      }
    }
  }
}

// softmax over M=2000 (sums NSPLA split-K partials) + hard-shrink + L1 renorm -> bf16
__global__ __launch_bounds__(256) void k_softmax(const float* __restrict__ sim, float* __restrict__ hdr,
                                                 ushort_t* __restrict__ wbf){
  __shared__ float e[2000];
  __shared__ float red[8];
  const int b = blockIdx.x, tid = threadIdx.x;
  const float znb = sqrtf(hdr[H_ZN+b]);
  float part = 0.f;
  for (int m=tid;m<2000;m+=256){
    size_t ix = (size_t)b*2000+m;
    float sv = 0.f;
    #pragma unroll
    for (int j=0;j<NSPLA;j++) sv += sim[ix + (size_t)j*SIMSTRIDE];
    float mnb = sqrtf(hdr[H_MN+m]);
    float s = sv / fmaxf(znb * mnb, 1e-8f);
    float ev = __expf(s);
    e[m] = ev; part += ev;
  }
  for (int o=32;o;o>>=1) part += __shfl_down(part,o,64);
  if ((tid&63)==0) red[tid>>6] = part;
  __syncthreads();
  const float denom = red[0]+red[1]+red[2]+red[3];
  const float t = 1.0f/2000.0f;
  float part2 = 0.f;
  for (int m=tid;m<2000;m+=256){
    float w = e[m]/denom;
    float d = w - t;
    float sh = fmaxf(d,0.f)*w/(fabsf(d)+0.01f);
    e[m] = sh; part2 += sh;
  }
  for (int o=32;o;o>>=1) part2 += __shfl_down(part2,o,64);
  if ((tid&63)==0) red[4+(tid>>6)] = part2;
  __syncthreads();
  const float inv = 1.0f/(red[4]+red[5]+red[6]+red[7]);
  for (int m=tid;m<2016;m+=256){
    ushort_t o = 0;
    if (m < 2000) o = f2bf(e[m]*inv);
    wbf[(size_t)b*2016+m] = o;
  }
}

// ---------------- deconv0 (MFMA): 64->64, k3 s2 p0, 6->13; out: G0CL [b][169][64] raw bf16 ----------------
__global__ __launch_bounds__(256) void k_deconv0m(
    const float* __restrict__ zh, const ushort_t* __restrict__ WPK, const float* __restrict__ b0g,
    float* __restrict__ hdr, ushort_t* __restrict__ out){
  __shared__ ushort_t inp[64*64];      // [cell 8x8 halo][ci64], chunk-swizzled
  const int b = blockIdx.x, tid = threadIdx.x;
  // zero the halo tile (8 KB = 512 uint4)
  for (int i = tid; i < 512; i += 256) ((uint4*)inp)[i] = make_uint4(0,0,0,0);
  __syncthreads();
  // coalesced partial-sum read: 2304 floats = 576 f32x4 groups (36%4==0 -> group stays in one ci)
  for (int i = tid; i < 576; i += 256){
    int idx = i*4;
    f32x4 v = *(const f32x4*)&zh[(size_t)b*2304 + idx];
    #pragma unroll
    for (int j=1;j<NSPLB;j++)
      v += *(const f32x4*)&zh[(size_t)b*2304 + idx + (size_t)j*ZHSTRIDE];
    int ci = idx/36;
    int p  = idx - ci*36;
    int chunk = ci >> 3, cil = ci & 7;
    #pragma unroll
    for (int e2=0;e2<4;e2++){
      int pp = p + e2;
      int r6 = pp/6, c6 = pp - r6*6;
      int cell = (r6+1)*8 + (c6+1);
      int slot = chunk ^ ((cell>>1)&7);
      inp[cell*64 + slot*8 + cil] = f2bf(v[e2]);
    }
  }
  __syncthreads();
  const int wv = tid>>6, lane = tid&63, r = lane&15, q = lane>>4;
  float biasr[4];
  #pragma unroll
  for (int v=0;v<4;v++) biasr[v] = b0g[wv*16 + q*4 + v];
  const int NCOL[4]={7,6,7,6}, NPOS[4]={49,42,42,36}, NT[4]={4,3,3,3},
            NCH[4]={8,4,4,2}, KB[4]={0,16384,24576,32768}, KK[4]={256,128,128,64},
            PI[4]={0,0,1,1}, PJ[4]={0,1,0,1};
  const int TOFF[4][4] = {{9,8,1,0},{9,1,0,0},{9,8,0,0},{9,0,0,0}};
  float sacc[4]={0,0,0,0}, qacc[4]={0,0,0,0};
  #pragma unroll
  for (int cl=0; cl<4; cl++){
    bf16x8 af[8];
    #pragma unroll
    for (int m=0;m<NCH[cl];m++)
      af[m] = *(const bf16x8*)(WPK + OD0 + KB[cl] + (wv*16+r)*KK[cl] + m*32 + q*8);
    for (int t = 0; t < NT[cl]; t++){
      int p = t*16 + r;
      bool ok = p < NPOS[cl];
      int pc = ok ? p : 0;
      int a_ = pc/NCOL[cl], c_ = pc - a_*NCOL[cl];
      int pb = a_*8 + c_;
      f32x4 acc = {0.f,0.f,0.f,0.f};
      #pragma unroll
      for (int m=0;m<NCH[cl];m++){
        int cell = pb + TOFF[cl][m>>1];
        int chunk = (m&1)*4 + q;
        int slot = chunk ^ ((cell>>1)&7);
        bf16x8 bv = *(const bf16x8*)&inp[cell*64 + slot*8];
        acc = __builtin_amdgcn_mfma_f32_16x16x32_bf16(af[m], bv, acc, 0, 0, 0);
      }
      if (ok){
        int pos = (2*a_+PI[cl])*13 + (2*c_+PJ[cl]);
        ushort_t pk[4];
        #pragma unroll
        for (int reg=0;reg<4;reg++){
          float y = acc[reg] + biasr[reg];
          pk[reg] = f2bf(y);
          sacc[reg] += y; qacc[reg] += y*y;
        }
        *(uint2*)&out[((size_t)b*169 + pos)*64 + wv*16 + q*4] =
          make_uint2((uint32_t)pk[0] | ((uint32_t)pk[1]<<16), (uint32_t)pk[2] | ((uint32_t)pk[3]<<16));
      }
    }
  }
  float* bk = bkt(hdr, b);
  #pragma unroll
  for (int reg=0;reg<4;reg++){
    float s = sacc[reg], qq = qacc[reg];
    for (int o=8;o;o>>=1){ s += __shfl_down(s,o,16); qq += __shfl_down(qq,o,16); }
    if (r==0){ atomicAdd(&bk[H_DS0+wv*16+q*4+reg], s); atomicAdd(&bk[H_DQ0+wv*16+q*4+reg], qq); }
  }
}

// ---------------- deconv1 (MFMA): 64->32, k3 s2 p1, 13->25; in: G0CL, out: G1CL [b][625][32] ----------------
__global__ __launch_bounds__(256) void k_deconv1m(
    const ushort_t* __restrict__ g0, const ushort_t* __restrict__ WPK, const float* __restrict__ b1g,
    const float* __restrict__ g, const float* __restrict__ be,
    float* __restrict__ hdr, ushort_t* __restrict__ out){
  __shared__ ushort_t inp[169*64];     // [cell 13x13][ci64], chunk-swizzled
  __shared__ float ac[128];
  const int b = blockIdx.x, tid = threadIdx.x;
  coef_lds(hdr, H_DS0, H_DQ0, g, be, ac, 64, 1.f/(512.f*169.f), tid);
  __syncthreads();
  for (int e = tid; e < 169*8; e += 256){
    int cell = e>>3, ch = e&7;
    uint4 raw = *(const uint4*)&g0[((size_t)b*169 + cell)*64 + ch*8];
    uint4 val = stage_chunk(raw, ac, ch*8, 64);
    int slot = ch ^ ((cell>>1)&7);
    *(uint4*)&inp[cell*64 + slot*8] = val;
  }
  __syncthreads();
  const int wv = tid>>6, lane = tid&63, r = lane&15, q = lane>>4;
  const int cotile = wv&1, ph = wv>>1;
  float biasr[4];
  #pragma unroll
  for (int v=0;v<4;v++) biasr[v] = b1g[cotile*16 + q*4 + v];
  const int NCOL[4]={13,12,13,12}, NPOS[4]={169,156,156,144}, NT[4]={11,10,10,9},
            NCH[4]={2,4,4,8}, KB[4]={0,2048,6144,10240}, KK[4]={64,128,128,256},
            PI[4]={0,0,1,1}, PJ[4]={0,1,0,1};
  const int TOFF[4][4] = {{0,0,0,0},{1,0,0,0},{13,0,0,0},{14,13,1,0}};
  float sacc[4]={0,0,0,0}, qacc[4]={0,0,0,0};
  #pragma unroll
  for (int cl=0; cl<4; cl++){
    bf16x8 af[8];
    #pragma unroll
    for (int m=0;m<NCH[cl];m++)
      af[m] = *(const bf16x8*)(WPK + OD1 + KB[cl] + (cotile*16+r)*KK[cl] + m*32 + q*8);
    for (int t = ph; t < NT[cl]; t += 2){
      int p = t*16 + r;
      bool ok = p < NPOS[cl];
      int pc = ok ? p : 0;
      int a_ = pc/NCOL[cl], c_ = pc - a_*NCOL[cl];
      int pb = a_*13 + c_;
      f32x4 acc = {0.f,0.f,0.f,0.f};
      #pragma unroll
      for (int m=0;m<NCH[cl];m++){
        int cell = pb + TOFF[cl][m>>1];
        int chunk = (m&1)*4 + q;
        int slot = chunk ^ ((cell>>1)&7);
        bf16x8 bv = *(const bf16x8*)&inp[cell*64 + slot*8];
        acc = __builtin_amdgcn_mfma_f32_16x16x32_bf16(af[m], bv, acc, 0, 0, 0);
      }
      if (ok){
        int pos = (2*a_+PI[cl])*25 + (2*c_+PJ[cl]);
        ushort_t pk[4];
        #pragma unroll
        for (int reg=0;reg<4;reg++){
          float y = acc[reg] + biasr[reg];
          pk[reg] = f2bf(y);
          sacc[reg] += y; qacc[reg] += y*y;
        }
        *(uint2*)&out[((size_t)b*625 + pos)*32 + cotile*16 + q*4] =
          make_uint2((uint32_t)pk[0] | ((uint32_t)pk[1]<<16), (uint32_t)pk[2] | ((uint32_t)pk[3]<<16));
      }
    }
  }
  float* bk = bkt(hdr, b);
  #pragma unroll
  for (int reg=0;reg<4;reg++){
    float s = sacc[reg], qq = qacc[reg];
    for (int o=8;o;o>>=1){ s += __shfl_down(s,o,16); qq += __shfl_down(qq,o,16); }
    if (r==0){ atomicAdd(&bk[H_DS1+cotile*16+q*4+reg], s); atomicAdd(&bk[H_DQ1+cotile*16+q*4+reg], qq); }
  }
}

// ---------------- deconv2 (MFMA): 32->16, k2 s2 p1 op1, 25->49; out: G2BF [b][cl][625][16] ----------------
__global__ __launch_bounds__(256) void k_deconv2m(
    const ushort_t* __restrict__ g1, const ushort_t* __restrict__ WPK, const float* __restrict__ bg,
    const float* __restrict__ g, const float* __restrict__ be,
    float* __restrict__ hdr, ushort_t* __restrict__ out){
  __shared__ ushort_t inp[625*32];     // [cell 25x25][ci32], chunk-swizzled
  __shared__ float ac[64];
  const int b = blockIdx.x, tid = threadIdx.x;
  coef_lds(hdr, H_DS1, H_DQ1, g, be, ac, 32, 1.f/(512.f*625.f), tid);
  __syncthreads();
  for (int e = tid; e < 625*4; e += 256){
    int cell = e>>2, ch = e&3;
    uint4 raw = *(const uint4*)&g1[((size_t)b*625 + cell)*32 + ch*8];
    uint4 val = stage_chunk(raw, ac, ch*8, 32);
    int slot = ch ^ ((cell>>1)&3);
    *(uint4*)&inp[cell*32 + slot*8] = val;
  }
  __syncthreads();
  const int wv = tid>>6, lane = tid&63, r = lane&15, q = lane>>4;
  const int cl = wv;   // one parity class per wave
  float biasr[4];
  #pragma unroll
  for (int v=0;v<4;v++) biasr[v] = bg[q*4 + v];
  const int NCOL[4]={25,24,25,24}, NPOS[4]={625,600,600,576}, NT[4]={40,38,38,36},
            TOFF[4]={0,1,25,26};
  const int nc = NCOL[cl], npos = NPOS[cl], nt = NT[cl], toff = TOFF[cl];
  bf16x8 af = *(const bf16x8*)(WPK + OD2 + cl*512 + r*32 + q*8);
  float sacc[4]={0,0,0,0}, qacc[4]={0,0,0,0};
  for (int t = 0; t < nt; t++){
    int p = t*16 + r;
    bool ok = p < npos;
    int pc = ok ? p : 0;
    int a_ = pc/nc, c_ = pc - a_*nc;
    int cell = a_*25 + c_ + toff;
    int slot = q ^ ((cell>>1)&3);
    f32x4 acc = {0.f,0.f,0.f,0.f};
    bf16x8 bv = *(const bf16x8*)&inp[cell*32 + slot*8];
    acc = __builtin_amdgcn_mfma_f32_16x16x32_bf16(af, bv, acc, 0, 0, 0);
    if (ok){
      ushort_t pk[4];
      #pragma unroll
      for (int reg=0;reg<4;reg++){
        float y = acc[reg] + biasr[reg];
        pk[reg] = f2bf(y);
        sacc[reg] += y; qacc[reg] += y*y;
      }
      *(uint2*)&out[(((size_t)b*4 + cl)*625 + p)*16 + q*4] =
        make_uint2((uint32_t)pk[0] | ((uint32_t)pk[1]<<16), (uint32_t)pk[2] | ((uint32_t)pk[3]<<16));
    }
  }
  float* bk = bkt(hdr, b);
  #pragma unroll
  for (int reg=0;reg<4;reg++){
    float s = sacc[reg], qq = qacc[reg];
    for (int o=8;o;o>>=1){ s += __shfl_down(s,o,16); qq += __shfl_down(qq,o,16); }
    if (r==0){ atomicAdd(&bk[H_DS2+q*4+reg], s); atomicAdd(&bk[H_DQ2+q*4+reg], qq); }
  }
}

// ---------------- deconv3: input-location-per-thread; G2BF channel-last -> 2x uint4 loads ----------------
__global__ __launch_bounds__(256) void k_deconv3(const ushort_t* __restrict__ g2, const float* __restrict__ w,
                                                 const float* __restrict__ bias,
                                                 const float* __restrict__ g, const float* __restrict__ be,
                                                 float* __restrict__ hdr, float* __restrict__ out){
  __shared__ float ac[32];
  __shared__ float wl[64];
  const int tid = threadIdx.x;
  coef_lds(hdr, H_DS2, H_DQ2, g, be, ac, 16, 1.f/(512.f*2401.f), tid);
  if (tid >= 64 && tid < 128) wl[tid-64] = w[tid-64];
  __syncthreads();
  int idx = blockIdx.x*256 + tid;
  if (idx >= 512*2401) return;
  int b = idx / 2401; int loc = idx - b*2401;
  int ii = loc / 49, jj = loc - ii*49;
  int pi = ii & 1, pj = jj & 1, cl = pi*2 + pj;
  int a = ii >> 1, c = jj >> 1;
  int nc = pj ? 24 : 25;
  const float b0 = bias[0];
  float acc00 = b0, acc01 = b0, acc10 = b0, acc11 = b0;
  const ushort_t* gp = g2 + (((size_t)b*4 + cl)*625 + a*nc + c)*16;
  ushort_t rv[16];
  *(uint4*)&rv[0] = *(const uint4*)(gp);
  *(uint4*)&rv[8] = *(const uint4*)(gp + 8);
  #pragma unroll
  for (int ci=0; ci<16; ci++){
    float raw = bf2f(rv[ci]);
    float h = fmaxf(fmaf(ac[ci], raw, ac[16+ci]), 0.f);
    acc00 = fmaf(h, wl[ci*4+0], acc00);
    acc01 = fmaf(h, wl[ci*4+1], acc01);
    acc10 = fmaf(h, wl[ci*4+2], acc10);
    acc11 = fmaf(h, wl[ci*4+3], acc11);
  }
  float* op = out + (size_t)b*9604 + (2*ii)*98 + 2*jj;
  op[0]   = 1.f/(1.f + __expf(-acc00));
  op[1]   = 1.f/(1.f + __expf(-acc01));
  op[98]  = 1.f/(1.f + __expf(-acc10));
  op[99]  = 1.f/(1.f + __expf(-acc11));
}

// ======================================================================
extern "C" void kernel_launch(void* const* d_in, const int* in_sizes, int n_in,
                              void* d_out, int out_size, void* d_ws, size_t ws_size,
                              hipStream_t stream){
  (void)in_sizes; (void)n_in; (void)out_size; (void)ws_size;
  const float* x     = (const float*)d_in[0];
  const float* c1w   = (const float*)d_in[1];
  const float* c1b   = (const float*)d_in[2];
  const float* bn1g  = (const float*)d_in[3];
  const float* bn1b  = (const float*)d_in[4];
  const float* c2w   = (const float*)d_in[5];
  const float* c2b   = (const float*)d_in[6];
  const float* bn2g  = (const float*)d_in[7];
  const float* bn2b  = (const float*)d_in[8];
  const float* c3w   = (const float*)d_in[9];
  const float* c3b   = (const float*)d_in[10];
  const float* bn3g  = (const float*)d_in[11];
  const float* bn3b  = (const float*)d_in[12];
  const float* c4w   = (const float*)d_in[13];
  const float* c4b   = (const float*)d_in[14];
  const float* bn4g  = (const float*)d_in[15];
  const float* bn4b  = (const float*)d_in[16];
  const float* mem   = (const float*)d_in[17];
  const float* d0w   = (const float*)d_in[18];
  const float* d0b   = (const float*)d_in[19];
  const float* dbn0g = (const float*)d_in[20];
  const float* dbn0b = (const float*)d_in[21];
  const float* d1w   = (const float*)d_in[22];
  const float* d1b   = (const float*)d_in[23];
  const float* dbn1g = (const float*)d_in[24];
  const float* dbn1b = (const float*)d_in[25];
  const float* d2w   = (const float*)d_in[26];
  const float* d2b   = (const float*)d_in[27];
  const float* dbn2g = (const float*)d_in[28];
  const float* dbn2b = (const float*)d_in[29];
  const float* d3w   = (const float*)d_in[30];
  const float* d3b   = (const float*)d_in[31];

  float* hdr  = (float*)d_ws;
  float* H2f  = hdr + HDR_FLOATS;        // slot: H2CL bf16 (10.24M ushort) / later G1CL
  float* H3f  = H2f + 10240000;          // slot: H3CL bf16 (5.54M ushort) / later G0CL
  float* ZRAW = H3f + 5537792;           // 512*2304 fp32
  float* WSLOT= ZRAW + 1179648;          // 73728 floats (holds WPK bf16)
  float* G2   = WSLOT + 73728;           // 19.67M floats scratch region
  ushort_t* MEMBF = (ushort_t*)(G2 + 19668992); // 2000*2304
  ushort_t* MEMT  = MEMBF + 4608000;            // 2304*2016
  ushort_t* ZBF   = MEMT + 4644864;             // 512*2304 (unused this rev)
  ushort_t* WBF   = ZBF + 1179648;              // 512*2016
  ushort_t* WPK   = (ushort_t*)WSLOT;
  float* SIMP = G2;                      // NSPLA * 512*2000 = 8.19M floats
  float* ZHP  = G2 + (size_t)NSPLA*SIMSTRIDE;   // NSPLB * 512*2304 = 8.26M floats
  ushort_t* G2BF = (ushort_t*)G2;        // 512*4*625*16 bf16 (SIMP/ZHP dead by then)
  ushort_t* H2CL = (ushort_t*)H2f;
  ushort_t* H3CL = (ushort_t*)H3f;
  ushort_t* G0CL = (ushort_t*)H3f;       // reuse (H3CL dead after conv4m)
  ushort_t* G1CL = (ushort_t*)H2f;       // reuse (H2CL dead after conv3m)
  float* OUT = (float*)d_out;

  hipMemsetAsync(hdr, 0, HDR_FLOATS*sizeof(float), stream);
  k_prep     <<<PREP_TOT, 256, 0, stream>>>(mem, MEMBF, MEMT, hdr,
                                            c2w, c3w, c4w, d0w, d1w, d2w, WPK, x);
  k_conv2m   <<<1024, 256, 0, stream>>>(x, WPK, c2b, c1w, c1b, bn1g, bn1b, hdr, H2CL);
  k_conv3m   <<<1024, 256, 0, stream>>>(H2CL, WPK, c3b, bn2g, bn2b, hdr, H3CL);
  k_conv4m   <<<512, 256, 0, stream>>>(H3CL, WPK, c4b, bn3g, bn3b, hdr, ZRAW);
  k_gemmA    <<<512, 256, 0, stream>>>(ZRAW, MEMBF, SIMP, bn4g, bn4b, hdr);
  k_softmax  <<<512, 256, 0, stream>>>(SIMP, hdr, WBF);
  k_gemmB    <<<504, 256, 0, stream>>>(WBF, MEMT, ZHP, 18, 2304, 2016, 63, 72, 9, ZHSTRIDE);
  k_deconv0m <<<512, 256, 0, stream>>>(ZHP, WPK, d0b, hdr, G0CL);
  k_deconv1m <<<512, 256, 0, stream>>>(G0CL, WPK, d1b, dbn0g, dbn0b, hdr, G1CL);
  k_deconv2m <<<512, 256, 0, stream>>>(G1CL, WPK, d2b, dbn1g, dbn1b, hdr, G2BF);
  k_deconv3  <<<4802, 256, 0, stream>>>(G2BF, d3w, d3b, dbn2g, dbn2b, hdr, OUT);
}